// Round 1
// baseline (15862.186 us; speedup 1.0000x reference)
//
#include <hip/hip_runtime.h>
#include <hip/hip_bf16.h>
#include <math.h>

// Problem constants
#define BB 32
#define SS 744
#define DD 512
#define HH 8
#define HDD 64
#define LL 4
#define EXPAND 4
#define NROWS (BB * SS)            // 23808
#define NBUF ((size_t)NROWS * DD)  // 12,189,696 floats per [B,S,D] buffer
#define SQRT_D 22.62741699796952f

// ---------------------------------------------------------------------------
// Embedding + positional encoding: h[b,s,:] = emb[x[b,s]] * sqrt(D) + pe[s,:]
// grid = B*S blocks, 128 threads (one float4 per thread)
// ---------------------------------------------------------------------------
__global__ __launch_bounds__(128) void k_embed(const int* __restrict__ x,
                                               const float* __restrict__ emb,
                                               const float* __restrict__ pe,
                                               float* __restrict__ h) {
    int row = blockIdx.x;            // b*S + s
    int s = row % SS;
    int tok = x[row];
    int t = threadIdx.x;             // 0..127
    float4 e = ((const float4*)(emb + (size_t)tok * DD))[t];
    float4 p = ((const float4*)(pe + (size_t)s * DD))[t];
    float4 o;
    o.x = e.x * SQRT_D + p.x;
    o.y = e.y * SQRT_D + p.y;
    o.z = e.z * SQRT_D + p.z;
    o.w = e.w * SQRT_D + p.w;
    ((float4*)(h + (size_t)row * DD))[t] = o;
}

// ---------------------------------------------------------------------------
// QKV projection: q[b,h,s,e] = sum_d h[b,s,h*64+d] * Wq[e,d]   (same W all heads)
// grid = (B*H, 24 s-tiles of 32), 256 threads
// ---------------------------------------------------------------------------
__global__ __launch_bounds__(256) void k_qkv(const float* __restrict__ h,
                                             const float* __restrict__ Wq,
                                             const float* __restrict__ Wk,
                                             const float* __restrict__ Wv,
                                             float* __restrict__ q,
                                             float* __restrict__ k,
                                             float* __restrict__ v) {
    int bh = blockIdx.x;             // 0..255
    int st = blockIdx.y;             // 0..23
    int b = bh >> 3, hh = bh & 7;
    int t = threadIdx.x;
    // stride 65: bank = (e + d) % 32 -> 2-way across 64 lanes = free
    __shared__ float wqs[64][65], wks[64][65], wvs[64][65];
    __shared__ float xs[32][68];

    for (int i = t; i < 4096; i += 256) {
        int e = i >> 6, d = i & 63;
        wqs[e][d] = Wq[i];
        wks[e][d] = Wk[i];
        wvs[e][d] = Wv[i];
    }
    int s0 = st * 32;
    for (int j = t; j < 512; j += 256) {    // 512 float4 slots = 32 rows x 16
        int r = j >> 4, c4 = (j & 15) * 4;
        int s = s0 + r; if (s >= SS) s = SS - 1;
        float4 val = *(const float4*)(h + ((size_t)b * SS + s) * DD + hh * HDD + c4);
        xs[r][c4 + 0] = val.x; xs[r][c4 + 1] = val.y;
        xs[r][c4 + 2] = val.z; xs[r][c4 + 3] = val.w;
    }
    __syncthreads();

    int e = t & 63, rb = t >> 6;     // lane = e (conflict-free weight reads)
#pragma unroll
    for (int ri = 0; ri < 8; ri++) {
        int r = ri * 4 + rb;
        float aq = 0.f, ak = 0.f, av = 0.f;
#pragma unroll
        for (int d = 0; d < 64; d++) {
            float xv = xs[r][d];
            aq += xv * wqs[e][d];
            ak += xv * wks[e][d];
            av += xv * wvs[e][d];
        }
        int s = s0 + r;
        if (s < SS) {
            size_t o = ((size_t)bh * SS + s) * HDD + e;
            q[o] = aq; k[o] = ak; v[o] = av;
        }
    }
}

// ---------------------------------------------------------------------------
// Flash-style attention, fp32. grid = (B*H, 24 q-tiles of 32), 256 threads.
// Online softmax over 24 k-tiles of 32. O accumulator: 8 floats/thread.
// Output written as [B,S,D] with d = h*64 + e.
// ---------------------------------------------------------------------------
__global__ __launch_bounds__(256) void k_attn(const float* __restrict__ q,
                                              const float* __restrict__ k,
                                              const float* __restrict__ v,
                                              float* __restrict__ ao) {
    int bh = blockIdx.x;
    int qt = blockIdx.y;
    int b = bh >> 3, hh = bh & 7;
    int t = threadIdx.x;
    __shared__ float Qs[32][68], Ks[32][68], Vs[32][68];
    __shared__ float Ps[32][33];
    __shared__ float mrow[32], lrow[32], arow[32];

    const float* qb = q + (size_t)bh * SS * HDD;
    const float* kb = k + (size_t)bh * SS * HDD;
    const float* vb = v + (size_t)bh * SS * HDD;

    int q0 = qt * 32;
    for (int j = t; j < 512; j += 256) {
        int r = j >> 4, c4 = (j & 15) * 4;
        int s = q0 + r; if (s >= SS) s = SS - 1;
        float4 val = *(const float4*)(qb + (size_t)s * HDD + c4);
        Qs[r][c4 + 0] = val.x; Qs[r][c4 + 1] = val.y;
        Qs[r][c4 + 2] = val.z; Qs[r][c4 + 3] = val.w;
    }
    if (t < 32) { mrow[t] = -INFINITY; lrow[t] = 0.f; }

    float oacc[8] = {0.f, 0.f, 0.f, 0.f, 0.f, 0.f, 0.f, 0.f};
    int orow = t >> 3, oc0 = (t & 7) * 8;

    for (int kt = 0; kt < 24; kt++) {
        int k0 = kt * 32;
        __syncthreads();   // protects Ks/Vs/Ps/arow from previous iteration
        for (int j = t; j < 512; j += 256) {
            int r = j >> 4, c4 = (j & 15) * 4;
            int s = k0 + r; if (s >= SS) s = SS - 1;
            float4 kv4 = *(const float4*)(kb + (size_t)s * HDD + c4);
            Ks[r][c4 + 0] = kv4.x; Ks[r][c4 + 1] = kv4.y;
            Ks[r][c4 + 2] = kv4.z; Ks[r][c4 + 3] = kv4.w;
            float4 vv4 = *(const float4*)(vb + (size_t)s * HDD + c4);
            Vs[r][c4 + 0] = vv4.x; Vs[r][c4 + 1] = vv4.y;
            Vs[r][c4 + 2] = vv4.z; Vs[r][c4 + 3] = vv4.w;
        }
        __syncthreads();
        // scores: row = t>>3, cols j = (t&7) + 8*jj  (broadcast-friendly banks)
#pragma unroll
        for (int jj = 0; jj < 4; jj++) {
            int j = (t & 7) + 8 * jj;
            float acc = 0.f;
#pragma unroll
            for (int d = 0; d < 64; d++) acc += Qs[orow][d] * Ks[j][d];
            Ps[orow][j] = (k0 + j < SS) ? acc * 0.125f : -INFINITY;
        }
        __syncthreads();
        if (t < 32) {
            float mold = mrow[t];
            float mnew = mold;
#pragma unroll
            for (int j = 0; j < 32; j++) mnew = fmaxf(mnew, Ps[t][j]);
            float alpha = __expf(mold - mnew);   // exp(-inf)=0 on first tile
            float lsum = lrow[t] * alpha;
#pragma unroll
            for (int j = 0; j < 32; j++) {
                float p = __expf(Ps[t][j] - mnew);
                Ps[t][j] = p;
                lsum += p;
            }
            mrow[t] = mnew; lrow[t] = lsum; arow[t] = alpha;
        }
        __syncthreads();
        float al = arow[orow];
#pragma unroll
        for (int i = 0; i < 8; i++) oacc[i] *= al;
        for (int j = 0; j < 32; j++) {
            float p = Ps[orow][j];
#pragma unroll
            for (int i = 0; i < 8; i++) oacc[i] += p * Vs[j][oc0 + i];
        }
    }
    int s = q0 + orow;
    if (s < SS) {
        float inv = 1.f / lrow[orow];
        float* dst = ao + ((size_t)b * SS + s) * DD + hh * HDD + oc0;
#pragma unroll
        for (int i = 0; i < 8; i++) dst[i] = oacc[i] * inv;
    }
}

// ---------------------------------------------------------------------------
// Generic tiled GEMM: C[M,N] = act(A[M,K] @ W[N,K]^T + bias[N])
// 64x64 tile, 256 threads, 4x4 micro-tile, K-chunk 16, prefetched.
// All dims divide tile sizes exactly for this problem.
// ---------------------------------------------------------------------------
template <bool RELU>
__global__ __launch_bounds__(256) void k_gemm(const float* __restrict__ A,
                                              const float* __restrict__ W,
                                              const float* __restrict__ bias,
                                              float* __restrict__ C,
                                              int M, int N, int K) {
    __shared__ float As[64][17];
    __shared__ float Ws[64][17];
    int row0 = blockIdx.x * 64;
    int n0b  = blockIdx.y * 64;
    int t = threadIdx.x;
    int tm4 = (t >> 4) * 4, tn4 = (t & 15) * 4;
    int lm = t >> 2, lk4 = (t & 3) * 4;

    const float* Ag = A + (size_t)(row0 + lm) * K + lk4;
    const float* Wg = W + (size_t)(n0b + lm) * K + lk4;

    float acc[4][4] = {};
    float4 av = *(const float4*)Ag;
    float4 wv = *(const float4*)Wg;

    for (int k0 = 0; k0 < K; k0 += 16) {
        __syncthreads();
        As[lm][lk4 + 0] = av.x; As[lm][lk4 + 1] = av.y;
        As[lm][lk4 + 2] = av.z; As[lm][lk4 + 3] = av.w;
        Ws[lm][lk4 + 0] = wv.x; Ws[lm][lk4 + 1] = wv.y;
        Ws[lm][lk4 + 2] = wv.z; Ws[lm][lk4 + 3] = wv.w;
        __syncthreads();
        if (k0 + 16 < K) {                 // prefetch next chunk over compute
            av = *(const float4*)(Ag + k0 + 16);
            wv = *(const float4*)(Wg + k0 + 16);
        }
#pragma unroll
        for (int kk = 0; kk < 16; kk++) {
            float a0 = As[tm4 + 0][kk], a1 = As[tm4 + 1][kk];
            float a2 = As[tm4 + 2][kk], a3 = As[tm4 + 3][kk];
            float w0 = Ws[tn4 + 0][kk], w1 = Ws[tn4 + 1][kk];
            float w2 = Ws[tn4 + 2][kk], w3 = Ws[tn4 + 3][kk];
            acc[0][0] += a0 * w0; acc[0][1] += a0 * w1; acc[0][2] += a0 * w2; acc[0][3] += a0 * w3;
            acc[1][0] += a1 * w0; acc[1][1] += a1 * w1; acc[1][2] += a1 * w2; acc[1][3] += a1 * w3;
            acc[2][0] += a2 * w0; acc[2][1] += a2 * w1; acc[2][2] += a2 * w2; acc[2][3] += a2 * w3;
            acc[3][0] += a3 * w0; acc[3][1] += a3 * w1; acc[3][2] += a3 * w2; acc[3][3] += a3 * w3;
        }
    }
    float b0 = bias[n0b + tn4 + 0], b1 = bias[n0b + tn4 + 1];
    float b2 = bias[n0b + tn4 + 2], b3 = bias[n0b + tn4 + 3];
#pragma unroll
    for (int i = 0; i < 4; i++) {
        int m = row0 + tm4 + i;
        float4 o;
        o.x = acc[i][0] + b0; o.y = acc[i][1] + b1;
        o.z = acc[i][2] + b2; o.w = acc[i][3] + b3;
        if (RELU) {
            o.x = fmaxf(o.x, 0.f); o.y = fmaxf(o.y, 0.f);
            o.z = fmaxf(o.z, 0.f); o.w = fmaxf(o.w, 0.f);
        }
        *(float4*)(C + (size_t)m * N + n0b + tn4) = o;
    }
}

// ---------------------------------------------------------------------------
// Fused residual add + LayerNorm: out = LN(a + b) * w + bias
// grid = NROWS blocks, 128 threads (one float4 per thread over D=512)
// ---------------------------------------------------------------------------
__global__ __launch_bounds__(128) void k_add_ln(const float* __restrict__ a,
                                                const float* __restrict__ b,
                                                const float* __restrict__ w,
                                                const float* __restrict__ bias,
                                                float* __restrict__ out) {
    int row = blockIdx.x;
    int t = threadIdx.x;
    float4 xa = ((const float4*)(a + (size_t)row * DD))[t];
    float4 xb = ((const float4*)(b + (size_t)row * DD))[t];
    float4 vv;
    vv.x = xa.x + xb.x; vv.y = xa.y + xb.y;
    vv.z = xa.z + xb.z; vv.w = xa.w + xb.w;
    float s  = vv.x + vv.y + vv.z + vv.w;
    float sq = vv.x * vv.x + vv.y * vv.y + vv.z * vv.z + vv.w * vv.w;
#pragma unroll
    for (int off = 32; off > 0; off >>= 1) {
        s  += __shfl_down(s, off);
        sq += __shfl_down(sq, off);
    }
    __shared__ float red[4];
    if ((t & 63) == 0) { red[(t >> 6) * 2] = s; red[(t >> 6) * 2 + 1] = sq; }
    __syncthreads();
    float S1 = red[0] + red[2], S2 = red[1] + red[3];
    float mean = S1 * (1.f / DD);
    float var  = S2 * (1.f / DD) - mean * mean;
    float inv  = rsqrtf(var + 1e-5f);
    float4 wv = ((const float4*)w)[t];
    float4 bv = ((const float4*)bias)[t];
    float4 o;
    o.x = (vv.x - mean) * inv * wv.x + bv.x;
    o.y = (vv.y - mean) * inv * wv.y + bv.y;
    o.z = (vv.z - mean) * inv * wv.z + bv.z;
    o.w = (vv.w - mean) * inv * wv.w + bv.w;
    ((float4*)(out + (size_t)row * DD))[t] = o;
}

// ---------------------------------------------------------------------------
extern "C" void kernel_launch(void* const* d_in, const int* in_sizes, int n_in,
                              void* d_out, int out_size, void* d_ws, size_t ws_size,
                              hipStream_t stream) {
    const int*   x    = (const int*)d_in[0];
    const float* emb  = (const float*)d_in[1];
    const float* pe   = (const float*)d_in[2];
    const float* Wq   = (const float*)d_in[3];
    const float* Wk   = (const float*)d_in[4];
    const float* Wv   = (const float*)d_in[5];
    const float* Wo   = (const float*)d_in[6];
    const float* bo   = (const float*)d_in[7];
    const float* ln1w = (const float*)d_in[8];
    const float* ln1b = (const float*)d_in[9];
    const float* W1   = (const float*)d_in[10];
    const float* b1   = (const float*)d_in[11];
    const float* W2   = (const float*)d_in[12];
    const float* b2   = (const float*)d_in[13];
    const float* ln2w = (const float*)d_in[14];
    const float* ln2b = (const float*)d_in[15];

    float* h  = (float*)d_out;            // [B,S,D] persistent hidden state
    float* ws = (float*)d_ws;
    float* qb = ws;                        // [B*H, S, 64]
    float* kb = qb + NBUF;
    float* vb = kb + NBUF;
    float* ao = vb + NBUF;                 // attention output [B,S,D]
    float* f1 = ao + NBUF;                 // FFN intermediate chunk [5952, 2048]
    float* wo_out = qb;                    // reuse q after attention
    float* n1     = kb;                    // reuse k
    float* ff     = vb;                    // reuse v

    k_embed<<<NROWS, 128, 0, stream>>>(x, emb, pe, h);

    for (int l = 0; l < LL; l++) {
        k_qkv<<<dim3(BB * HH, 24), 256, 0, stream>>>(
            h, Wq + (size_t)l * 4096, Wk + (size_t)l * 4096, Wv + (size_t)l * 4096,
            qb, kb, vb);
        k_attn<<<dim3(BB * HH, 24), 256, 0, stream>>>(qb, kb, vb, ao);
        k_gemm<false><<<dim3(NROWS / 64, DD / 64), 256, 0, stream>>>(
            ao, Wo + (size_t)l * DD * DD, bo + (size_t)l * DD, wo_out,
            NROWS, DD, DD);
        k_add_ln<<<NROWS, 128, 0, stream>>>(wo_out, h,
            ln1w + (size_t)l * DD, ln1b + (size_t)l * DD, n1);
        // FFN in 4 row-chunks of 5952 so the 2048-wide intermediate fits f1
        for (int c = 0; c < 4; c++) {
            const float* Ain = n1 + (size_t)c * 5952 * DD;
            k_gemm<true><<<dim3(5952 / 64, (EXPAND * DD) / 64), 256, 0, stream>>>(
                Ain, W1 + (size_t)l * EXPAND * DD * DD, b1 + (size_t)l * EXPAND * DD,
                f1, 5952, EXPAND * DD, DD);
            k_gemm<false><<<dim3(5952 / 64, DD / 64), 256, 0, stream>>>(
                f1, W2 + (size_t)l * DD * EXPAND * DD, b2 + (size_t)l * DD,
                ff + (size_t)c * 5952 * DD, 5952, DD, EXPAND * DD);
        }
        k_add_ln<<<NROWS, 128, 0, stream>>>(ff, n1,
            ln2w + (size_t)l * DD, ln2b + (size_t)l * DD, h);
    }
}

// Round 2
// 6876.376 us; speedup vs baseline: 2.3068x; 2.3068x over previous
//
#include <hip/hip_runtime.h>
#include <hip/hip_bf16.h>
#include <math.h>

// Problem constants
#define BB 32
#define SS 744
#define DD 512
#define HH 8
#define HDD 64
#define LL 4
#define EXPAND 4
#define NROWS (BB * SS)            // 23808
#define NBUF ((size_t)NROWS * DD)  // 12,189,696 floats per [B,S,D] buffer
#define SQRT_D 22.62741699796952f

typedef __hip_bfloat16 bf16;
typedef __attribute__((ext_vector_type(8))) __bf16 bf16x8;
typedef __attribute__((ext_vector_type(4))) float f32x4;

// ---------------------------------------------------------------------------
// Embedding + positional encoding
// ---------------------------------------------------------------------------
__global__ __launch_bounds__(128) void k_embed(const int* __restrict__ x,
                                               const float* __restrict__ emb,
                                               const float* __restrict__ pe,
                                               float* __restrict__ h) {
    int row = blockIdx.x;
    int s = row % SS;
    int tok = x[row];
    int t = threadIdx.x;
    float4 e = ((const float4*)(emb + (size_t)tok * DD))[t];
    float4 p = ((const float4*)(pe + (size_t)s * DD))[t];
    float4 o;
    o.x = e.x * SQRT_D + p.x;
    o.y = e.y * SQRT_D + p.y;
    o.z = e.z * SQRT_D + p.z;
    o.w = e.w * SQRT_D + p.w;
    ((float4*)(h + (size_t)row * DD))[t] = o;
}

// ---------------------------------------------------------------------------
// fp32 -> bf16 conversion (grid-stride)
// ---------------------------------------------------------------------------
__global__ __launch_bounds__(256) void k_f2b(const float* __restrict__ in,
                                             bf16* __restrict__ out, int n) {
    for (int i = blockIdx.x * 256 + threadIdx.x; i < n; i += gridDim.x * 256)
        out[i] = __float2bfloat16(in[i]);
}

// ---------------------------------------------------------------------------
// QKV projection (fp32, small): q[bh,s,e] = sum_d h[b,s,h*64+d] * Wq[e,d]
// ---------------------------------------------------------------------------
__global__ __launch_bounds__(256) void k_qkv(const float* __restrict__ h,
                                             const float* __restrict__ Wq,
                                             const float* __restrict__ Wk,
                                             const float* __restrict__ Wv,
                                             float* __restrict__ q,
                                             float* __restrict__ k,
                                             float* __restrict__ v) {
    int bh = blockIdx.x;
    int st = blockIdx.y;
    int b = bh >> 3, hh = bh & 7;
    int t = threadIdx.x;
    __shared__ float wqs[64][65], wks[64][65], wvs[64][65];
    __shared__ float xs[32][68];

    for (int i = t; i < 4096; i += 256) {
        int e = i >> 6, d = i & 63;
        wqs[e][d] = Wq[i];
        wks[e][d] = Wk[i];
        wvs[e][d] = Wv[i];
    }
    int s0 = st * 32;
    for (int j = t; j < 512; j += 256) {
        int r = j >> 4, c4 = (j & 15) * 4;
        int s = s0 + r; if (s >= SS) s = SS - 1;
        float4 val = *(const float4*)(h + ((size_t)b * SS + s) * DD + hh * HDD + c4);
        xs[r][c4 + 0] = val.x; xs[r][c4 + 1] = val.y;
        xs[r][c4 + 2] = val.z; xs[r][c4 + 3] = val.w;
    }
    __syncthreads();

    int e = t & 63, rb = t >> 6;
#pragma unroll
    for (int ri = 0; ri < 8; ri++) {
        int r = ri * 4 + rb;
        float aq = 0.f, ak = 0.f, av = 0.f;
#pragma unroll
        for (int d = 0; d < 64; d++) {
            float xv = xs[r][d];
            aq += xv * wqs[e][d];
            ak += xv * wks[e][d];
            av += xv * wvs[e][d];
        }
        int s = s0 + r;
        if (s < SS) {
            size_t o = ((size_t)bh * SS + s) * HDD + e;
            q[o] = aq; k[o] = ak; v[o] = av;
        }
    }
}

// ---------------------------------------------------------------------------
// Flash-style attention, fp32 compute, bf16 output (feeds Wo MFMA GEMM).
// ---------------------------------------------------------------------------
__global__ __launch_bounds__(256) void k_attn(const float* __restrict__ q,
                                              const float* __restrict__ k,
                                              const float* __restrict__ v,
                                              bf16* __restrict__ ao) {
    int bh = blockIdx.x;
    int qt = blockIdx.y;
    int b = bh >> 3, hh = bh & 7;
    int t = threadIdx.x;
    __shared__ float Qs[32][68], Ks[32][68], Vs[32][68];
    __shared__ float Ps[32][33];
    __shared__ float mrow[32], lrow[32], arow[32];

    const float* qb = q + (size_t)bh * SS * HDD;
    const float* kb = k + (size_t)bh * SS * HDD;
    const float* vb = v + (size_t)bh * SS * HDD;

    int q0 = qt * 32;
    for (int j = t; j < 512; j += 256) {
        int r = j >> 4, c4 = (j & 15) * 4;
        int s = q0 + r; if (s >= SS) s = SS - 1;
        float4 val = *(const float4*)(qb + (size_t)s * HDD + c4);
        Qs[r][c4 + 0] = val.x; Qs[r][c4 + 1] = val.y;
        Qs[r][c4 + 2] = val.z; Qs[r][c4 + 3] = val.w;
    }
    if (t < 32) { mrow[t] = -INFINITY; lrow[t] = 0.f; }

    float oacc[8] = {0.f, 0.f, 0.f, 0.f, 0.f, 0.f, 0.f, 0.f};
    int orow = t >> 3, oc0 = (t & 7) * 8;

    for (int kt = 0; kt < 24; kt++) {
        int k0 = kt * 32;
        __syncthreads();
        for (int j = t; j < 512; j += 256) {
            int r = j >> 4, c4 = (j & 15) * 4;
            int s = k0 + r; if (s >= SS) s = SS - 1;
            float4 kv4 = *(const float4*)(kb + (size_t)s * HDD + c4);
            Ks[r][c4 + 0] = kv4.x; Ks[r][c4 + 1] = kv4.y;
            Ks[r][c4 + 2] = kv4.z; Ks[r][c4 + 3] = kv4.w;
            float4 vv4 = *(const float4*)(vb + (size_t)s * HDD + c4);
            Vs[r][c4 + 0] = vv4.x; Vs[r][c4 + 1] = vv4.y;
            Vs[r][c4 + 2] = vv4.z; Vs[r][c4 + 3] = vv4.w;
        }
        __syncthreads();
#pragma unroll
        for (int jj = 0; jj < 4; jj++) {
            int j = (t & 7) + 8 * jj;
            float acc = 0.f;
#pragma unroll
            for (int d = 0; d < 64; d++) acc += Qs[orow][d] * Ks[j][d];
            Ps[orow][j] = (k0 + j < SS) ? acc * 0.125f : -INFINITY;
        }
        __syncthreads();
        if (t < 32) {
            float mold = mrow[t];
            float mnew = mold;
#pragma unroll
            for (int j = 0; j < 32; j++) mnew = fmaxf(mnew, Ps[t][j]);
            float alpha = __expf(mold - mnew);
            float lsum = lrow[t] * alpha;
#pragma unroll
            for (int j = 0; j < 32; j++) {
                float p = __expf(Ps[t][j] - mnew);
                Ps[t][j] = p;
                lsum += p;
            }
            mrow[t] = mnew; lrow[t] = lsum; arow[t] = alpha;
        }
        __syncthreads();
        float al = arow[orow];
#pragma unroll
        for (int i = 0; i < 8; i++) oacc[i] *= al;
        for (int j = 0; j < 32; j++) {
            float p = Ps[orow][j];
#pragma unroll
            for (int i = 0; i < 8; i++) oacc[i] += p * Vs[j][oc0 + i];
        }
    }
    int s = q0 + orow;
    if (s < SS) {
        float inv = 1.f / lrow[orow];
        bf16* dst = ao + ((size_t)b * SS + s) * DD + hh * HDD + oc0;
#pragma unroll
        for (int i = 0; i < 8; i++) dst[i] = __float2bfloat16(oacc[i] * inv);
    }
}

// ---------------------------------------------------------------------------
// bf16 MFMA GEMM (m97 pattern): C[M,N] = act(A[M,K] @ W[N,K]^T + bias)
// 128x128 tile, 256 threads (4 waves in 2x2), BK=32, 16x16x32 bf16 MFMA,
// global_load_lds width 16. Requires M%128==0, N%128==0, K%32==0.
// OUT_BF16: store bf16 (for FFN1 -> FFN2 chaining), else fp32.
// ---------------------------------------------------------------------------
template <bool RELU, bool OUT_BF16>
__global__ __launch_bounds__(256) void k_gemm_mfma(const bf16* __restrict__ A,
                                                   const bf16* __restrict__ W,
                                                   const float* __restrict__ bias,
                                                   void* __restrict__ Cout,
                                                   int M, int N, int K) {
    __shared__ __align__(16) bf16 As[128 * 32];
    __shared__ __align__(16) bf16 Ws[128 * 32];
    int t = threadIdx.x;
    int wave = t >> 6, lane = t & 63;
    int m0 = blockIdx.x * 128, n0 = blockIdx.y * 128;
    int wm = (wave >> 1) * 64, wn = (wave & 1) * 64;
    int fr = lane & 15, fq = lane >> 4;   // frag row / quad

    f32x4 acc[4][4] = {};

    // staging geometry: tile is 128 rows x 64 bytes (32 bf16). Each
    // global_load_lds issue moves 64 lanes x 16B = 1KB; 8KB tile = 8 issues
    // = 2 rounds x 4 waves.
    int base0 = (wave << 10) + lane * 16;        // round 0 byte offset
    int base1 = base0 + 4096;                    // round 1
    int r0 = base0 >> 6, c0 = (base0 & 63) >> 1; // row, elem-col
    int r1 = base1 >> 6, c1 = (base1 & 63) >> 1;

    for (int k0 = 0; k0 < K; k0 += 32) {
        __syncthreads();
        __builtin_amdgcn_global_load_lds(
            (const __attribute__((address_space(1))) void*)(A + (size_t)(m0 + r0) * K + k0 + c0),
            (__attribute__((address_space(3))) void*)((char*)As + (wave << 10)),
            16, 0, 0);
        __builtin_amdgcn_global_load_lds(
            (const __attribute__((address_space(1))) void*)(A + (size_t)(m0 + r1) * K + k0 + c1),
            (__attribute__((address_space(3))) void*)((char*)As + (wave << 10) + 4096),
            16, 0, 0);
        __builtin_amdgcn_global_load_lds(
            (const __attribute__((address_space(1))) void*)(W + (size_t)(n0 + r0) * K + k0 + c0),
            (__attribute__((address_space(3))) void*)((char*)Ws + (wave << 10)),
            16, 0, 0);
        __builtin_amdgcn_global_load_lds(
            (const __attribute__((address_space(1))) void*)(W + (size_t)(n0 + r1) * K + k0 + c1),
            (__attribute__((address_space(3))) void*)((char*)Ws + (wave << 10) + 4096),
            16, 0, 0);
        __syncthreads();   // compiler drains vmcnt before s_barrier

        bf16x8 af[4], bfr[4];
#pragma unroll
        for (int i = 0; i < 4; i++)
            af[i] = *(const bf16x8*)(As + (wm + i * 16 + fr) * 32 + fq * 8);
#pragma unroll
        for (int i = 0; i < 4; i++)
            bfr[i] = *(const bf16x8*)(Ws + (wn + i * 16 + fr) * 32 + fq * 8);
#pragma unroll
        for (int mi = 0; mi < 4; mi++)
#pragma unroll
            for (int ni = 0; ni < 4; ni++)
                acc[mi][ni] = __builtin_amdgcn_mfma_f32_16x16x32_bf16(
                    af[mi], bfr[ni], acc[mi][ni], 0, 0, 0);
    }

    // epilogue: D[row][col] with col=lane&15, row=fq*4+reg
    float bv[4];
#pragma unroll
    for (int ni = 0; ni < 4; ni++) bv[ni] = bias[n0 + wn + ni * 16 + fr];
#pragma unroll
    for (int mi = 0; mi < 4; mi++) {
#pragma unroll
        for (int r = 0; r < 4; r++) {
            int mg = m0 + wm + mi * 16 + fq * 4 + r;
#pragma unroll
            for (int ni = 0; ni < 4; ni++) {
                float val = acc[mi][ni][r] + bv[ni];
                if (RELU) val = fmaxf(val, 0.f);
                int ng = n0 + wn + ni * 16 + fr;
                if (OUT_BF16)
                    ((bf16*)Cout)[(size_t)mg * N + ng] = __float2bfloat16(val);
                else
                    ((float*)Cout)[(size_t)mg * N + ng] = val;
            }
        }
    }
}

// ---------------------------------------------------------------------------
// Fused residual add + LayerNorm; optionally also writes a bf16 copy.
// ---------------------------------------------------------------------------
template <bool WB16>
__global__ __launch_bounds__(128) void k_add_ln(const float* __restrict__ a,
                                                const float* __restrict__ b,
                                                const float* __restrict__ w,
                                                const float* __restrict__ bias,
                                                float* __restrict__ out,
                                                bf16* __restrict__ out16) {
    int row = blockIdx.x;
    int t = threadIdx.x;
    float4 xa = ((const float4*)(a + (size_t)row * DD))[t];
    float4 xb = ((const float4*)(b + (size_t)row * DD))[t];
    float4 vv;
    vv.x = xa.x + xb.x; vv.y = xa.y + xb.y;
    vv.z = xa.z + xb.z; vv.w = xa.w + xb.w;
    float s  = vv.x + vv.y + vv.z + vv.w;
    float sq = vv.x * vv.x + vv.y * vv.y + vv.z * vv.z + vv.w * vv.w;
#pragma unroll
    for (int off = 32; off > 0; off >>= 1) {
        s  += __shfl_down(s, off);
        sq += __shfl_down(sq, off);
    }
    __shared__ float red[4];
    if ((t & 63) == 0) { red[(t >> 6) * 2] = s; red[(t >> 6) * 2 + 1] = sq; }
    __syncthreads();
    float S1 = red[0] + red[2], S2 = red[1] + red[3];
    float mean = S1 * (1.f / DD);
    float var  = S2 * (1.f / DD) - mean * mean;
    float inv  = rsqrtf(var + 1e-5f);
    float4 wv = ((const float4*)w)[t];
    float4 bv = ((const float4*)bias)[t];
    float4 o;
    o.x = (vv.x - mean) * inv * wv.x + bv.x;
    o.y = (vv.y - mean) * inv * wv.y + bv.y;
    o.z = (vv.z - mean) * inv * wv.z + bv.z;
    o.w = (vv.w - mean) * inv * wv.w + bv.w;
    ((float4*)(out + (size_t)row * DD))[t] = o;
    if (WB16) {
        bf16 h0 = __float2bfloat16(o.x), h1 = __float2bfloat16(o.y);
        bf16 h2 = __float2bfloat16(o.z), h3 = __float2bfloat16(o.w);
        ushort4 u;
        u.x = *(unsigned short*)&h0; u.y = *(unsigned short*)&h1;
        u.z = *(unsigned short*)&h2; u.w = *(unsigned short*)&h3;
        ((ushort4*)(out16 + (size_t)row * DD))[t] = u;
    }
}

// ---------------------------------------------------------------------------
extern "C" void kernel_launch(void* const* d_in, const int* in_sizes, int n_in,
                              void* d_out, int out_size, void* d_ws, size_t ws_size,
                              hipStream_t stream) {
    const int*   x    = (const int*)d_in[0];
    const float* emb  = (const float*)d_in[1];
    const float* pe   = (const float*)d_in[2];
    const float* Wq   = (const float*)d_in[3];
    const float* Wk   = (const float*)d_in[4];
    const float* Wv   = (const float*)d_in[5];
    const float* Wo   = (const float*)d_in[6];
    const float* bo   = (const float*)d_in[7];
    const float* ln1w = (const float*)d_in[8];
    const float* ln1b = (const float*)d_in[9];
    const float* W1   = (const float*)d_in[10];
    const float* b1   = (const float*)d_in[11];
    const float* W2   = (const float*)d_in[12];
    const float* b2   = (const float*)d_in[13];
    const float* ln2w = (const float*)d_in[14];
    const float* ln2b = (const float*)d_in[15];

    float* h  = (float*)d_out;
    float* ws = (float*)d_ws;
    float* qb = ws;                        // q  -> wo_out -> ff
    float* kb = qb + NBUF;                 // k  -> n1 (fp32)
    float* vb = kb + NBUF;                 // v  -> f1 (bf16, 2*NBUF elems)
    bf16*  aob = (bf16*)(vb + NBUF);       // attention out, bf16 [NROWS, D]
    bf16*  n1b = aob + NBUF;               // n1 bf16 copy   [NROWS, D]
    bf16*  wob16 = n1b + NBUF;             // Wo bf16: 4 x 512 x 512
    bf16*  w1b16 = wob16 + (size_t)LL * DD * DD;          // 4 x 2048 x 512
    bf16*  w2b16 = w1b16 + (size_t)LL * EXPAND * DD * DD; // 4 x 512 x 2048
    bf16*  f1b  = (bf16*)vb;               // FFN intermediate [11904, 2048] bf16
    float* wo_out = qb;
    float* n1     = kb;
    float* ff     = qb;

    // one-time (per launch) weight conversions
    k_f2b<<<2048, 256, 0, stream>>>(Wo, wob16, LL * DD * DD);
    k_f2b<<<4096, 256, 0, stream>>>(W1, w1b16, LL * EXPAND * DD * DD);
    k_f2b<<<4096, 256, 0, stream>>>(W2, w2b16, LL * EXPAND * DD * DD);

    k_embed<<<NROWS, 128, 0, stream>>>(x, emb, pe, h);

    for (int l = 0; l < LL; l++) {
        k_qkv<<<dim3(BB * HH, 24), 256, 0, stream>>>(
            h, Wq + (size_t)l * 4096, Wk + (size_t)l * 4096, Wv + (size_t)l * 4096,
            qb, kb, vb);
        k_attn<<<dim3(BB * HH, 24), 256, 0, stream>>>(qb, kb, vb, aob);
        // Wo projection: [23808,512] x [512,512]^T
        k_gemm_mfma<false, false><<<dim3(NROWS / 128, DD / 128), 256, 0, stream>>>(
            aob, wob16 + (size_t)l * DD * DD, bo + (size_t)l * DD, wo_out,
            NROWS, DD, DD);
        k_add_ln<true><<<NROWS, 128, 0, stream>>>(wo_out, h,
            ln1w + (size_t)l * DD, ln1b + (size_t)l * DD, n1, n1b);
        // FFN in 2 row-chunks of 11904 (f1 bf16 fits in vb's NBUF floats)
        for (int c = 0; c < 2; c++) {
            const bf16* Ain = n1b + (size_t)c * 11904 * DD;
            k_gemm_mfma<true, true><<<dim3(11904 / 128, (EXPAND * DD) / 128), 256, 0, stream>>>(
                Ain, w1b16 + (size_t)l * EXPAND * DD * DD, b1 + (size_t)l * EXPAND * DD,
                f1b, 11904, EXPAND * DD, DD);
            k_gemm_mfma<false, false><<<dim3(11904 / 128, DD / 128), 256, 0, stream>>>(
                f1b, w2b16 + (size_t)l * DD * EXPAND * DD, b2 + (size_t)l * DD,
                ff + (size_t)c * 11904 * DD, 11904, DD, EXPAND * DD);
        }
        k_add_ln<false><<<NROWS, 128, 0, stream>>>(ff, n1,
            ln2w + (size_t)l * DD, ln2b + (size_t)l * DD, h, nullptr);
    }
}

// Round 3
// 1919.305 us; speedup vs baseline: 8.2645x; 3.5827x over previous
//
#include <hip/hip_runtime.h>
#include <hip/hip_bf16.h>
#include <math.h>

// Problem constants
#define BB 32
#define SS 744
#define DD 512
#define HH 8
#define HDD 64
#define LL 4
#define EXPAND 4
#define NROWS (BB * SS)            // 23808
#define MROWS (NROWS * HH)         // 190464 = 1488 * 128
#define NBUF ((size_t)NROWS * DD)  // 12,189,696 floats per [B,S,D] buffer
#define SQRT_D 22.62741699796952f

typedef __hip_bfloat16 bf16;
typedef __attribute__((ext_vector_type(8))) __bf16 bf16x8;
typedef __attribute__((ext_vector_type(4))) float f32x4;

#define GPTR(p) (const __attribute__((address_space(1))) void*)(p)
#define LPTR(p) (__attribute__((address_space(3))) void*)(p)

// ---------------------------------------------------------------------------
// Embedding + positional encoding; writes fp32 h and bf16 h16
// ---------------------------------------------------------------------------
__global__ __launch_bounds__(128) void k_embed(const int* __restrict__ x,
                                               const float* __restrict__ emb,
                                               const float* __restrict__ pe,
                                               float* __restrict__ h,
                                               bf16* __restrict__ h16) {
    int row = blockIdx.x;
    int s = row % SS;
    int tok = x[row];
    int t = threadIdx.x;
    float4 e = ((const float4*)(emb + (size_t)tok * DD))[t];
    float4 p = ((const float4*)(pe + (size_t)s * DD))[t];
    float4 o;
    o.x = e.x * SQRT_D + p.x;
    o.y = e.y * SQRT_D + p.y;
    o.z = e.z * SQRT_D + p.z;
    o.w = e.w * SQRT_D + p.w;
    ((float4*)(h + (size_t)row * DD))[t] = o;
    bf16 b0 = __float2bfloat16(o.x), b1 = __float2bfloat16(o.y);
    bf16 b2 = __float2bfloat16(o.z), b3 = __float2bfloat16(o.w);
    ushort4 u;
    u.x = *(unsigned short*)&b0; u.y = *(unsigned short*)&b1;
    u.z = *(unsigned short*)&b2; u.w = *(unsigned short*)&b3;
    ((ushort4*)(h16 + (size_t)row * DD))[t] = u;
}

// ---------------------------------------------------------------------------
// fp32 -> bf16 conversion (grid-stride)
// ---------------------------------------------------------------------------
__global__ __launch_bounds__(256) void k_f2b(const float* __restrict__ in,
                                             bf16* __restrict__ out, int n) {
    for (int i = blockIdx.x * 256 + threadIdx.x; i < n; i += gridDim.x * 256)
        out[i] = __float2bfloat16(in[i]);
}

// ---------------------------------------------------------------------------
// QKV projection as one MFMA GEMM: A = h16 as [(b,s,h)][64], W = [192][64]
// (Wq rows 0-63 | Wk 64-127 | Wv 128-191). Output: qk [row][128], v [row][64].
// Tile 128 x 192, K=64 one-shot. grid = MROWS/128 = 1488.
// ---------------------------------------------------------------------------
__global__ __launch_bounds__(256) void k_qkv_mfma(const bf16* __restrict__ A,
                                                  const bf16* __restrict__ Wqkv,
                                                  bf16* __restrict__ qk,
                                                  bf16* __restrict__ v) {
    __shared__ __align__(16) bf16 As[2][128][32];
    __shared__ __align__(16) bf16 Ws[2][192][32];
    int t = threadIdx.x;
    int w = t >> 6, lane = t & 63;
    int fr = lane & 15, fq = lane >> 4;
    int m0 = blockIdx.x * 128;
    int wm = (w >> 1) * 64;        // row half
    int wc = (w & 1) * 96;         // col half
    int lr = lane >> 2, lc8 = (lane & 3) * 8;

#pragma unroll
    for (int kc = 0; kc < 2; kc++)
#pragma unroll
        for (int i = 0; i < 2; i++) {
            int rb = w * 32 + i * 16;
            __builtin_amdgcn_global_load_lds(
                GPTR(A + (size_t)(m0 + rb + lr) * 64 + kc * 32 + lc8),
                LPTR(&As[kc][rb][0]), 16, 0, 0);
        }
#pragma unroll
    for (int kc = 0; kc < 2; kc++)
#pragma unroll
        for (int i = 0; i < 3; i++) {
            int rb = w * 48 + i * 16;
            __builtin_amdgcn_global_load_lds(
                GPTR(Wqkv + (size_t)(rb + lr) * 64 + kc * 32 + lc8),
                LPTR(&Ws[kc][rb][0]), 16, 0, 0);
        }
    __syncthreads();

    bf16x8 af[2][4], bw[2][6];
#pragma unroll
    for (int kc = 0; kc < 2; kc++) {
#pragma unroll
        for (int mi = 0; mi < 4; mi++)
            af[kc][mi] = *(const bf16x8*)&As[kc][wm + mi * 16 + fr][fq * 8];
#pragma unroll
        for (int ni = 0; ni < 6; ni++)
            bw[kc][ni] = *(const bf16x8*)&Ws[kc][wc + ni * 16 + fr][fq * 8];
    }
    f32x4 acc[4][6] = {};
#pragma unroll
    for (int mi = 0; mi < 4; mi++)
#pragma unroll
        for (int ni = 0; ni < 6; ni++) {
            acc[mi][ni] = __builtin_amdgcn_mfma_f32_16x16x32_bf16(af[0][mi], bw[0][ni], acc[mi][ni], 0, 0, 0);
            acc[mi][ni] = __builtin_amdgcn_mfma_f32_16x16x32_bf16(af[1][mi], bw[1][ni], acc[mi][ni], 0, 0, 0);
        }

#pragma unroll
    for (int mi = 0; mi < 4; mi++)
#pragma unroll
        for (int r = 0; r < 4; r++) {
            size_t mg = m0 + wm + mi * 16 + fq * 4 + r;
#pragma unroll
            for (int ni = 0; ni < 6; ni++) {
                int col = wc + ni * 16 + fr;
                bf16 val = __float2bfloat16(acc[mi][ni][r]);
                if (col < 128) qk[mg * 128 + col] = val;
                else           v[mg * 64 + (col - 128)] = val;
            }
        }
}

// ---------------------------------------------------------------------------
// V transpose: v [(b,s,h)][64] -> vt [bh*64 + d][744]. grid (256, 12).
// ---------------------------------------------------------------------------
__global__ __launch_bounds__(256) void k_vt(const bf16* __restrict__ v,
                                            bf16* __restrict__ vt) {
    int bh = blockIdx.x, st = blockIdx.y;
    int b = bh >> 3, h = bh & 7;
    int t = threadIdx.x;
    __shared__ bf16 Ls[64][72];
    int s0 = st * 64;
    for (int j = t; j < 512; j += 256) {
        int si = j >> 3, e8 = (j & 7) * 8;
        int s = s0 + si; if (s > SS - 1) s = SS - 1;
        bf16x8 val = *(const bf16x8*)(v + ((size_t)(b * SS + s) * 8 + h) * 64 + e8);
        *(bf16x8*)&Ls[si][e8] = val;
    }
    __syncthreads();
    for (int j = t; j < 512; j += 256) {
        int d = j >> 3, s8 = (j & 7) * 8;
        if (s0 + s8 < SS) {
            __align__(16) bf16 tmp[8];
#pragma unroll
            for (int i = 0; i < 8; i++) tmp[i] = Ls[s8 + i][d];
            *(bf16x8*)(vt + ((size_t)bh * 64 + d) * SS + s0 + s8) = *(bf16x8*)tmp;
        }
    }
}

// ---------------------------------------------------------------------------
// Flash MFMA attention. grid (256 bh, 12 q-tiles of 64), 256 threads.
// qk: [(b,s,h)][128] (q cols 0-63, k cols 64-127), vt: [bh*64+d][744].
// ao: [b*744+s][512] bf16 at col h*64+d.
// ---------------------------------------------------------------------------
__global__ __launch_bounds__(256) void k_attn_mfma(const bf16* __restrict__ qk,
                                                   const bf16* __restrict__ vt,
                                                   bf16* __restrict__ ao) {
    int bh = blockIdx.x, qt = blockIdx.y;
    int b = bh >> 3, h = bh & 7;
    int t = threadIdx.x;
    int w = t >> 6, lane = t & 63;
    int fr = lane & 15, fq = lane >> 4;
    int lr = lane >> 2, lc8 = (lane & 3) * 8;
    int q0 = qt * 64;

    __shared__ __align__(16) bf16 Qs[2][64][32];
    __shared__ __align__(16) bf16 Ks[2][64][32];
    __shared__ __align__(16) bf16 Vs[2][64][32];
    __shared__ __align__(16) bf16 Ps[4][16][72];

    // stage Q (once): wave w loads rows w*16..w*16+16 of the tile
    {
        int row = q0 + w * 16 + lr;
        if (row > SS - 1) row = SS - 1;
        size_t gb = ((size_t)(b * SS + row) * 8 + h) * 128;
#pragma unroll
        for (int kc = 0; kc < 2; kc++)
            __builtin_amdgcn_global_load_lds(GPTR(qk + gb + kc * 32 + lc8),
                                             LPTR(&Qs[kc][w * 16][0]), 16, 0, 0);
    }
    __syncthreads();
    bf16x8 afq[2];
    afq[0] = *(const bf16x8*)&Qs[0][w * 16 + fr][fq * 8];
    afq[1] = *(const bf16x8*)&Qs[1][w * 16 + fr][fq * 8];

    f32x4 acc_o[4] = {};
    float m_[4] = {-1e30f, -1e30f, -1e30f, -1e30f};
    float l_[4] = {0.f, 0.f, 0.f, 0.f};

    for (int kt = 0; kt < 12; kt++) {
        int k0 = kt * 64;
        __syncthreads();   // previous iteration's frag reads done before restage
        {
            int row = k0 + w * 16 + lr;
            if (row > SS - 1) row = SS - 1;
            size_t gb = ((size_t)(b * SS + row) * 8 + h) * 128 + 64;
#pragma unroll
            for (int kc = 0; kc < 2; kc++)
                __builtin_amdgcn_global_load_lds(GPTR(qk + gb + kc * 32 + lc8),
                                                 LPTR(&Ks[kc][w * 16][0]), 16, 0, 0);
        }
        {
            int d = w * 16 + lr;
            size_t gb = ((size_t)bh * 64 + d) * SS;
#pragma unroll
            for (int kc = 0; kc < 2; kc++) {
                int key = k0 + kc * 32 + lc8;
                if (key > SS - 8) key = SS - 8;
                __builtin_amdgcn_global_load_lds(GPTR(vt + gb + key),
                                                 LPTR(&Vs[kc][w * 16][0]), 16, 0, 0);
            }
        }
        __syncthreads();

        // scores S[16 q-rows][64 keys] per wave
        f32x4 s[4] = {};
#pragma unroll
        for (int n = 0; n < 4; n++) {
            bf16x8 bk0 = *(const bf16x8*)&Ks[0][n * 16 + fr][fq * 8];
            bf16x8 bk1 = *(const bf16x8*)&Ks[1][n * 16 + fr][fq * 8];
            s[n] = __builtin_amdgcn_mfma_f32_16x16x32_bf16(afq[0], bk0, s[n], 0, 0, 0);
            s[n] = __builtin_amdgcn_mfma_f32_16x16x32_bf16(afq[1], bk1, s[n], 0, 0, 0);
        }
        // mask + scale
#pragma unroll
        for (int n = 0; n < 4; n++) {
            bool valid = (k0 + n * 16 + fr) < SS;
#pragma unroll
            for (int r = 0; r < 4; r++)
                s[n][r] = valid ? s[n][r] * 0.125f : -1e30f;
        }
        // online softmax per row (row = fq*4 + r; cols spread over lane&15)
#pragma unroll
        for (int r = 0; r < 4; r++) {
            float mx = fmaxf(fmaxf(s[0][r], s[1][r]), fmaxf(s[2][r], s[3][r]));
            mx = fmaxf(mx, __shfl_xor(mx, 1));
            mx = fmaxf(mx, __shfl_xor(mx, 2));
            mx = fmaxf(mx, __shfl_xor(mx, 4));
            mx = fmaxf(mx, __shfl_xor(mx, 8));
            float mnew = fmaxf(m_[r], mx);
            float alpha = __expf(m_[r] - mnew);
            m_[r] = mnew;
            float ls = 0.f;
#pragma unroll
            for (int n = 0; n < 4; n++) {
                float p = __expf(s[n][r] - mnew);
                s[n][r] = p;
                ls += p;
            }
            ls += __shfl_xor(ls, 1);
            ls += __shfl_xor(ls, 2);
            ls += __shfl_xor(ls, 4);
            ls += __shfl_xor(ls, 8);
            l_[r] = l_[r] * alpha + ls;
#pragma unroll
            for (int n = 0; n < 4; n++) acc_o[n][r] *= alpha;
        }
        // P: C-layout -> LDS -> A-layout (per-wave slab, wave-internal ordering)
#pragma unroll
        for (int n = 0; n < 4; n++)
#pragma unroll
            for (int r = 0; r < 4; r++)
                Ps[w][fq * 4 + r][n * 16 + fr] = __float2bfloat16(s[n][r]);
        bf16x8 afp0 = *(const bf16x8*)&Ps[w][fr][fq * 8];
        bf16x8 afp1 = *(const bf16x8*)&Ps[w][fr][32 + fq * 8];
        // PV
#pragma unroll
        for (int n = 0; n < 4; n++) {
            bf16x8 bv0 = *(const bf16x8*)&Vs[0][n * 16 + fr][fq * 8];
            bf16x8 bv1 = *(const bf16x8*)&Vs[1][n * 16 + fr][fq * 8];
            acc_o[n] = __builtin_amdgcn_mfma_f32_16x16x32_bf16(afp0, bv0, acc_o[n], 0, 0, 0);
            acc_o[n] = __builtin_amdgcn_mfma_f32_16x16x32_bf16(afp1, bv1, acc_o[n], 0, 0, 0);
        }
    }

#pragma unroll
    for (int r = 0; r < 4; r++) {
        int s_ = q0 + w * 16 + fq * 4 + r;
        if (s_ < SS) {
            float inv = 1.f / l_[r];
            bf16* dst = ao + ((size_t)(b * SS + s_) * 8 + h) * 64;
#pragma unroll
            for (int n = 0; n < 4; n++)
                dst[n * 16 + fr] = __float2bfloat16(acc_o[n][r] * inv);
        }
    }
}

// ---------------------------------------------------------------------------
// bf16 MFMA GEMM (m97 pattern): C[M,N] = act(A[M,K] @ W[N,K]^T + bias)
// ---------------------------------------------------------------------------
template <bool RELU, bool OUT_BF16>
__global__ __launch_bounds__(256) void k_gemm_mfma(const bf16* __restrict__ A,
                                                   const bf16* __restrict__ W,
                                                   const float* __restrict__ bias,
                                                   void* __restrict__ Cout,
                                                   int M, int N, int K) {
    __shared__ __align__(16) bf16 As[128 * 32];
    __shared__ __align__(16) bf16 Ws[128 * 32];
    int t = threadIdx.x;
    int wave = t >> 6, lane = t & 63;
    int m0 = blockIdx.x * 128, n0 = blockIdx.y * 128;
    int wm = (wave >> 1) * 64, wn = (wave & 1) * 64;
    int fr = lane & 15, fq = lane >> 4;

    f32x4 acc[4][4] = {};

    int base0 = (wave << 10) + lane * 16;
    int base1 = base0 + 4096;
    int r0 = base0 >> 6, c0 = (base0 & 63) >> 1;
    int r1 = base1 >> 6, c1 = (base1 & 63) >> 1;

    for (int k0 = 0; k0 < K; k0 += 32) {
        __syncthreads();
        __builtin_amdgcn_global_load_lds(GPTR(A + (size_t)(m0 + r0) * K + k0 + c0),
                                         LPTR((char*)As + (wave << 10)), 16, 0, 0);
        __builtin_amdgcn_global_load_lds(GPTR(A + (size_t)(m0 + r1) * K + k0 + c1),
                                         LPTR((char*)As + (wave << 10) + 4096), 16, 0, 0);
        __builtin_amdgcn_global_load_lds(GPTR(W + (size_t)(n0 + r0) * K + k0 + c0),
                                         LPTR((char*)Ws + (wave << 10)), 16, 0, 0);
        __builtin_amdgcn_global_load_lds(GPTR(W + (size_t)(n0 + r1) * K + k0 + c1),
                                         LPTR((char*)Ws + (wave << 10) + 4096), 16, 0, 0);
        __syncthreads();

        bf16x8 af[4], bfr[4];
#pragma unroll
        for (int i = 0; i < 4; i++)
            af[i] = *(const bf16x8*)(As + (wm + i * 16 + fr) * 32 + fq * 8);
#pragma unroll
        for (int i = 0; i < 4; i++)
            bfr[i] = *(const bf16x8*)(Ws + (wn + i * 16 + fr) * 32 + fq * 8);
#pragma unroll
        for (int mi = 0; mi < 4; mi++)
#pragma unroll
            for (int ni = 0; ni < 4; ni++)
                acc[mi][ni] = __builtin_amdgcn_mfma_f32_16x16x32_bf16(
                    af[mi], bfr[ni], acc[mi][ni], 0, 0, 0);
    }

    float bv[4];
#pragma unroll
    for (int ni = 0; ni < 4; ni++) bv[ni] = bias[n0 + wn + ni * 16 + fr];
#pragma unroll
    for (int mi = 0; mi < 4; mi++) {
#pragma unroll
        for (int r = 0; r < 4; r++) {
            int mg = m0 + wm + mi * 16 + fq * 4 + r;
#pragma unroll
            for (int ni = 0; ni < 4; ni++) {
                float val = acc[mi][ni][r] + bv[ni];
                if (RELU) val = fmaxf(val, 0.f);
                int ng = n0 + wn + ni * 16 + fr;
                if (OUT_BF16)
                    ((bf16*)Cout)[(size_t)mg * N + ng] = __float2bfloat16(val);
                else
                    ((float*)Cout)[(size_t)mg * N + ng] = val;
            }
        }
    }
}

// ---------------------------------------------------------------------------
// Fused residual add + LayerNorm; writes fp32 out + bf16 out16.
// ---------------------------------------------------------------------------
__global__ __launch_bounds__(128) void k_add_ln(const float* __restrict__ a,
                                                const float* __restrict__ b,
                                                const float* __restrict__ w,
                                                const float* __restrict__ bias,
                                                float* __restrict__ out,
                                                bf16* __restrict__ out16) {
    int row = blockIdx.x;
    int t = threadIdx.x;
    float4 xa = ((const float4*)(a + (size_t)row * DD))[t];
    float4 xb = ((const float4*)(b + (size_t)row * DD))[t];
    float4 vv;
    vv.x = xa.x + xb.x; vv.y = xa.y + xb.y;
    vv.z = xa.z + xb.z; vv.w = xa.w + xb.w;
    float s  = vv.x + vv.y + vv.z + vv.w;
    float sq = vv.x * vv.x + vv.y * vv.y + vv.z * vv.z + vv.w * vv.w;
#pragma unroll
    for (int off = 32; off > 0; off >>= 1) {
        s  += __shfl_down(s, off);
        sq += __shfl_down(sq, off);
    }
    __shared__ float red[4];
    if ((t & 63) == 0) { red[(t >> 6) * 2] = s; red[(t >> 6) * 2 + 1] = sq; }
    __syncthreads();
    float S1 = red[0] + red[2], S2 = red[1] + red[3];
    float mean = S1 * (1.f / DD);
    float var  = S2 * (1.f / DD) - mean * mean;
    float inv  = rsqrtf(var + 1e-5f);
    float4 wv = ((const float4*)w)[t];
    float4 bv = ((const float4*)bias)[t];
    float4 o;
    o.x = (vv.x - mean) * inv * wv.x + bv.x;
    o.y = (vv.y - mean) * inv * wv.y + bv.y;
    o.z = (vv.z - mean) * inv * wv.z + bv.z;
    o.w = (vv.w - mean) * inv * wv.w + bv.w;
    ((float4*)(out + (size_t)row * DD))[t] = o;
    bf16 h0 = __float2bfloat16(o.x), h1 = __float2bfloat16(o.y);
    bf16 h2 = __float2bfloat16(o.z), h3 = __float2bfloat16(o.w);
    ushort4 u;
    u.x = *(unsigned short*)&h0; u.y = *(unsigned short*)&h1;
    u.z = *(unsigned short*)&h2; u.w = *(unsigned short*)&h3;
    ((ushort4*)(out16 + (size_t)row * DD))[t] = u;
}

// ---------------------------------------------------------------------------
extern "C" void kernel_launch(void* const* d_in, const int* in_sizes, int n_in,
                              void* d_out, int out_size, void* d_ws, size_t ws_size,
                              hipStream_t stream) {
    const int*   x    = (const int*)d_in[0];
    const float* emb  = (const float*)d_in[1];
    const float* pe   = (const float*)d_in[2];
    const float* Wq   = (const float*)d_in[3];
    const float* Wk   = (const float*)d_in[4];
    const float* Wv   = (const float*)d_in[5];
    const float* Wo   = (const float*)d_in[6];
    const float* bo   = (const float*)d_in[7];
    const float* ln1w = (const float*)d_in[8];
    const float* ln1b = (const float*)d_in[9];
    const float* W1   = (const float*)d_in[10];
    const float* b1   = (const float*)d_in[11];
    const float* W2   = (const float*)d_in[12];
    const float* b2   = (const float*)d_in[13];
    const float* ln2w = (const float*)d_in[14];
    const float* ln2b = (const float*)d_in[15];

    float* h  = (float*)d_out;
    float* ws = (float*)d_ws;
    // Region A (NBUF floats): qk bf16 [MROWS][128] -> wo_out fp32 -> ff fp32
    bf16*  qkbuf  = (bf16*)ws;
    float* wo_out = ws;
    float* ff     = ws;
    // Region B (NBUF floats): [v bf16 MROWSx64][wqkv->vT bf16] -> f1b bf16
    bf16*  v_buf  = (bf16*)(ws + NBUF);
    bf16*  vt_buf = (bf16*)(ws + NBUF + NBUF / 2);
    bf16*  wqkv   = vt_buf;            // overlaid; dead before vT written
    bf16*  f1b    = v_buf;             // [11904][2048] spans region B
    // Region C: n1 fp32
    float* n1     = ws + 2 * NBUF;
    // Region D (NBUF/2 floats): aob -> n1b (bf16 [NROWS][512])
    bf16*  regD   = (bf16*)(ws + 3 * NBUF);
    // Region E: h16
    bf16*  h16    = regD + NBUF;
    // Weights (bf16)
    bf16*  wob16  = h16 + NBUF;
    bf16*  w1b16  = wob16 + (size_t)LL * DD * DD;
    bf16*  w2b16  = w1b16 + (size_t)LL * EXPAND * DD * DD;

    k_f2b<<<2048, 256, 0, stream>>>(Wo, wob16, LL * DD * DD);
    k_f2b<<<4096, 256, 0, stream>>>(W1, w1b16, LL * EXPAND * DD * DD);
    k_f2b<<<4096, 256, 0, stream>>>(W2, w2b16, LL * EXPAND * DD * DD);
    k_embed<<<NROWS, 128, 0, stream>>>(x, emb, pe, h, h16);

    for (int l = 0; l < LL; l++) {
        k_f2b<<<16, 256, 0, stream>>>(Wq + (size_t)l * 4096, wqkv, 4096);
        k_f2b<<<16, 256, 0, stream>>>(Wk + (size_t)l * 4096, wqkv + 4096, 4096);
        k_f2b<<<16, 256, 0, stream>>>(Wv + (size_t)l * 4096, wqkv + 8192, 4096);
        k_qkv_mfma<<<MROWS / 128, 256, 0, stream>>>(h16, wqkv, qkbuf, v_buf);
        k_vt<<<dim3(256, 12), 256, 0, stream>>>(v_buf, vt_buf);
        k_attn_mfma<<<dim3(256, 12), 256, 0, stream>>>(qkbuf, vt_buf, regD);
        k_gemm_mfma<false, false><<<dim3(NROWS / 128, DD / 128), 256, 0, stream>>>(
            regD, wob16 + (size_t)l * DD * DD, bo + (size_t)l * DD, wo_out,
            NROWS, DD, DD);
        k_add_ln<<<NROWS, 128, 0, stream>>>(wo_out, h,
            ln1w + (size_t)l * DD, ln1b + (size_t)l * DD, n1, regD /*n1b*/);
        for (int c = 0; c < 2; c++) {
            const bf16* Ain = regD + (size_t)c * 11904 * DD;
            k_gemm_mfma<true, true><<<dim3(11904 / 128, (EXPAND * DD) / 128), 256, 0, stream>>>(
                Ain, w1b16 + (size_t)l * EXPAND * DD * DD, b1 + (size_t)l * EXPAND * DD,
                f1b, 11904, EXPAND * DD, DD);
            k_gemm_mfma<false, false><<<dim3(11904 / 128, DD / 128), 256, 0, stream>>>(
                f1b, w2b16 + (size_t)l * DD * EXPAND * DD, b2 + (size_t)l * DD,
                ff + (size_t)c * 11904 * DD, 11904, DD, EXPAND * DD);
        }
        k_add_ln<<<NROWS, 128, 0, stream>>>(ff, n1,
            ln2w + (size_t)l * DD, ln2b + (size_t)l * DD, h, h16);
    }
}

// Round 4
// 1771.932 us; speedup vs baseline: 8.9519x; 1.0832x over previous
//
#include <hip/hip_runtime.h>
#include <hip/hip_bf16.h>
#include <math.h>

// Problem constants
#define BB 32
#define SS 744
#define DD 512
#define HH 8
#define HDD 64
#define LL 4
#define EXPAND 4
#define NROWS (BB * SS)            // 23808
#define MROWS (NROWS * HH)         // 190464 = 1488 * 128
#define NBUF ((size_t)NROWS * DD)  // 12,189,696 floats per [B,S,D] buffer
#define SQRT_D 22.62741699796952f

typedef __hip_bfloat16 bf16;
typedef __attribute__((ext_vector_type(8))) __bf16 bf16x8;
typedef __attribute__((ext_vector_type(4))) float f32x4;

#define GPTR(p) (const __attribute__((address_space(1))) void*)(p)
#define LPTR(p) (__attribute__((address_space(3))) void*)(p)

// ---------------------------------------------------------------------------
// Embedding + positional encoding; writes fp32 h and bf16 h16
// ---------------------------------------------------------------------------
__global__ __launch_bounds__(128) void k_embed(const int* __restrict__ x,
                                               const float* __restrict__ emb,
                                               const float* __restrict__ pe,
                                               float* __restrict__ h,
                                               bf16* __restrict__ h16) {
    int row = blockIdx.x;
    int s = row % SS;
    int tok = x[row];
    int t = threadIdx.x;
    float4 e = ((const float4*)(emb + (size_t)tok * DD))[t];
    float4 p = ((const float4*)(pe + (size_t)s * DD))[t];
    float4 o;
    o.x = e.x * SQRT_D + p.x;
    o.y = e.y * SQRT_D + p.y;
    o.z = e.z * SQRT_D + p.z;
    o.w = e.w * SQRT_D + p.w;
    ((float4*)(h + (size_t)row * DD))[t] = o;
    bf16 b0 = __float2bfloat16(o.x), b1 = __float2bfloat16(o.y);
    bf16 b2 = __float2bfloat16(o.z), b3 = __float2bfloat16(o.w);
    ushort4 u;
    u.x = *(unsigned short*)&b0; u.y = *(unsigned short*)&b1;
    u.z = *(unsigned short*)&b2; u.w = *(unsigned short*)&b3;
    ((ushort4*)(h16 + (size_t)row * DD))[t] = u;
}

// ---------------------------------------------------------------------------
// fp32 -> bf16 conversion (grid-stride)
// ---------------------------------------------------------------------------
__global__ __launch_bounds__(256) void k_f2b(const float* __restrict__ in,
                                             bf16* __restrict__ out, int n) {
    for (int i = blockIdx.x * 256 + threadIdx.x; i < n; i += gridDim.x * 256)
        out[i] = __float2bfloat16(in[i]);
}

// ---------------------------------------------------------------------------
// QKV projection as one MFMA GEMM: A = h16 as [(b,s,h)][64], W = [192][64]
// ---------------------------------------------------------------------------
__global__ __launch_bounds__(256) void k_qkv_mfma(const bf16* __restrict__ A,
                                                  const bf16* __restrict__ Wqkv,
                                                  bf16* __restrict__ qk,
                                                  bf16* __restrict__ v) {
    __shared__ __align__(16) bf16 As[2][128][32];
    __shared__ __align__(16) bf16 Ws[2][192][32];
    int t = threadIdx.x;
    int w = t >> 6, lane = t & 63;
    int fr = lane & 15, fq = lane >> 4;
    int m0 = blockIdx.x * 128;
    int wm = (w >> 1) * 64;        // row half
    int wc = (w & 1) * 96;         // col half
    int lr = lane >> 2, lc8 = (lane & 3) * 8;

#pragma unroll
    for (int kc = 0; kc < 2; kc++)
#pragma unroll
        for (int i = 0; i < 2; i++) {
            int rb = w * 32 + i * 16;
            __builtin_amdgcn_global_load_lds(
                GPTR(A + (size_t)(m0 + rb + lr) * 64 + kc * 32 + lc8),
                LPTR(&As[kc][rb][0]), 16, 0, 0);
        }
#pragma unroll
    for (int kc = 0; kc < 2; kc++)
#pragma unroll
        for (int i = 0; i < 3; i++) {
            int rb = w * 48 + i * 16;
            __builtin_amdgcn_global_load_lds(
                GPTR(Wqkv + (size_t)(rb + lr) * 64 + kc * 32 + lc8),
                LPTR(&Ws[kc][rb][0]), 16, 0, 0);
        }
    __syncthreads();

    bf16x8 af[2][4], bw[2][6];
#pragma unroll
    for (int kc = 0; kc < 2; kc++) {
#pragma unroll
        for (int mi = 0; mi < 4; mi++)
            af[kc][mi] = *(const bf16x8*)&As[kc][wm + mi * 16 + fr][fq * 8];
#pragma unroll
        for (int ni = 0; ni < 6; ni++)
            bw[kc][ni] = *(const bf16x8*)&Ws[kc][wc + ni * 16 + fr][fq * 8];
    }
    f32x4 acc[4][6] = {};
#pragma unroll
    for (int mi = 0; mi < 4; mi++)
#pragma unroll
        for (int ni = 0; ni < 6; ni++) {
            acc[mi][ni] = __builtin_amdgcn_mfma_f32_16x16x32_bf16(af[0][mi], bw[0][ni], acc[mi][ni], 0, 0, 0);
            acc[mi][ni] = __builtin_amdgcn_mfma_f32_16x16x32_bf16(af[1][mi], bw[1][ni], acc[mi][ni], 0, 0, 0);
        }

#pragma unroll
    for (int mi = 0; mi < 4; mi++)
#pragma unroll
        for (int r = 0; r < 4; r++) {
            size_t mg = m0 + wm + mi * 16 + fq * 4 + r;
#pragma unroll
            for (int ni = 0; ni < 6; ni++) {
                int col = wc + ni * 16 + fr;
                bf16 val = __float2bfloat16(acc[mi][ni][r]);
                if (col < 128) qk[mg * 128 + col] = val;
                else           v[mg * 64 + (col - 128)] = val;
            }
        }
}

// ---------------------------------------------------------------------------
// V transpose: v [(b,s,h)][64] -> vt [bh*64 + d][744]. grid (256, 12).
// ---------------------------------------------------------------------------
__global__ __launch_bounds__(256) void k_vt(const bf16* __restrict__ v,
                                            bf16* __restrict__ vt) {
    int bh = blockIdx.x, st = blockIdx.y;
    int b = bh >> 3, h = bh & 7;
    int t = threadIdx.x;
    __shared__ bf16 Ls[64][72];
    int s0 = st * 64;
    for (int j = t; j < 512; j += 256) {
        int si = j >> 3, e8 = (j & 7) * 8;
        int s = s0 + si; if (s > SS - 1) s = SS - 1;
        bf16x8 val = *(const bf16x8*)(v + ((size_t)(b * SS + s) * 8 + h) * 64 + e8);
        *(bf16x8*)&Ls[si][e8] = val;
    }
    __syncthreads();
    for (int j = t; j < 512; j += 256) {
        int d = j >> 3, s8 = (j & 7) * 8;
        if (s0 + s8 < SS) {
            __align__(16) bf16 tmp[8];
#pragma unroll
            for (int i = 0; i < 8; i++) tmp[i] = Ls[s8 + i][d];
            *(bf16x8*)(vt + ((size_t)bh * 64 + d) * SS + s0 + s8) = *(bf16x8*)tmp;
        }
    }
}

// ---------------------------------------------------------------------------
// Flash MFMA attention, S^T orientation. grid (256 bh, 6 q-tiles of 128).
// Per block: 4 waves, each owns 32 q-rows (2 x 16-row sets). 12 key-tiles of 64.
// S^T = K·Q^T puts qrow in the lane dim (col=fr): softmax reductions are
// 2 shuffles (xor 16/32); m/l/alpha are per-lane scalars. P stored row-major
// [qrow][key] (8B packed writes), read back as PV B-operand directly.
// O^T = V^T·P accumulates in C-layout (row=d, col=qrow).
// ---------------------------------------------------------------------------
__global__ __launch_bounds__(256) void k_attn_mfma(const bf16* __restrict__ qk,
                                                   const bf16* __restrict__ vt,
                                                   bf16* __restrict__ ao) {
    int bh = blockIdx.x, qt = blockIdx.y;
    int b = bh >> 3, h = bh & 7;
    int t = threadIdx.x;
    int w = t >> 6, lane = t & 63;
    int fr = lane & 15, fq = lane >> 4;
    int lr = lane >> 2, lc8 = (lane & 3) * 8;
    int q0 = qt * 128;

    __shared__ __align__(16) bf16 Ks[2][64][32];
    __shared__ __align__(16) bf16 Vs[2][64][32];
    __shared__ __align__(16) bf16 Ps[4][32][72];  // per-wave P[qrow][key], pad 8

    // Q fragments direct from global (once per block): B-frag Q[qrow][e]
    bf16x8 qf[2][2];
#pragma unroll
    for (int qs = 0; qs < 2; qs++) {
        int row = q0 + w * 32 + qs * 16 + fr;
        if (row > SS - 1) row = SS - 1;
        size_t gb = ((size_t)(b * SS + row) * 8 + h) * 128;
        qf[qs][0] = *(const bf16x8*)(qk + gb + fq * 8);
        qf[qs][1] = *(const bf16x8*)(qk + gb + 32 + fq * 8);
    }

    f32x4 o_acc[2][4] = {};                 // [qset][d-tile]
    float m_[2] = {-1e30f, -1e30f};
    float l_[2] = {0.f, 0.f};

    for (int kt = 0; kt < 12; kt++) {
        int k0 = kt * 64;
        __syncthreads();   // all waves done with Ks/Vs before restage
        {
            int row = k0 + w * 16 + lr;
            if (row > SS - 1) row = SS - 1;
            size_t gb = ((size_t)(b * SS + row) * 8 + h) * 128 + 64;
#pragma unroll
            for (int kc = 0; kc < 2; kc++)
                __builtin_amdgcn_global_load_lds(GPTR(qk + gb + kc * 32 + lc8),
                                                 LPTR(&Ks[kc][w * 16][0]), 16, 0, 0);
        }
        {
            int d = w * 16 + lr;
            size_t gb = ((size_t)bh * 64 + d) * SS;
#pragma unroll
            for (int kc = 0; kc < 2; kc++) {
                int key = k0 + kc * 32 + lc8;
                if (key > SS - 8) key = SS - 8;
                __builtin_amdgcn_global_load_lds(GPTR(vt + gb + key),
                                                 LPTR(&Vs[kc][w * 16][0]), 16, 0, 0);
            }
        }
        __syncthreads();

        // K fragments: A[m=key][k=e], shared across both q-sets
        bf16x8 kf[4][2];
#pragma unroll
        for (int n = 0; n < 4; n++) {
            kf[n][0] = *(const bf16x8*)&Ks[0][n * 16 + fr][fq * 8];
            kf[n][1] = *(const bf16x8*)&Ks[1][n * 16 + fr][fq * 8];
        }

#pragma unroll
        for (int qs = 0; qs < 2; qs++) {
            // S^T tiles: key m-dim (4 tiles), qrow n-dim (this q-set)
            f32x4 st[4] = {};
#pragma unroll
            for (int n = 0; n < 4; n++) {
                st[n] = __builtin_amdgcn_mfma_f32_16x16x32_bf16(kf[n][0], qf[qs][0], st[n], 0, 0, 0);
                st[n] = __builtin_amdgcn_mfma_f32_16x16x32_bf16(kf[n][1], qf[qs][1], st[n], 0, 0, 0);
            }
            // mask + scale: key = k0 + n*16 + fq*4 + r, qrow fixed per lane
#pragma unroll
            for (int n = 0; n < 4; n++) {
                int kbase = k0 + n * 16 + fq * 4;
#pragma unroll
                for (int r = 0; r < 4; r++)
                    st[n][r] = (kbase + r < SS) ? st[n][r] * 0.125f : -1e30f;
            }
            // online softmax: all 16 values in this lane share one qrow
            float mx = -1e30f;
#pragma unroll
            for (int n = 0; n < 4; n++)
#pragma unroll
                for (int r = 0; r < 4; r++) mx = fmaxf(mx, st[n][r]);
            mx = fmaxf(mx, __shfl_xor(mx, 16));
            mx = fmaxf(mx, __shfl_xor(mx, 32));
            float mnew = fmaxf(m_[qs], mx);
            float alpha = __expf(m_[qs] - mnew);
            m_[qs] = mnew;
            float ls = 0.f;
#pragma unroll
            for (int n = 0; n < 4; n++)
#pragma unroll
                for (int r = 0; r < 4; r++) {
                    float p = __expf(st[n][r] - mnew);
                    st[n][r] = p;
                    ls += p;
                }
            ls += __shfl_xor(ls, 16);
            ls += __shfl_xor(ls, 32);
            l_[qs] = l_[qs] * alpha + ls;
#pragma unroll
            for (int dt = 0; dt < 4; dt++)
#pragma unroll
                for (int r = 0; r < 4; r++) o_acc[qs][dt][r] *= alpha;
            // store P[qrow][key]: 4 consecutive keys per reg group -> 8B writes
#pragma unroll
            for (int n = 0; n < 4; n++) {
                __align__(8) bf16 tb[4];
#pragma unroll
                for (int r = 0; r < 4; r++) tb[r] = __float2bfloat16(st[n][r]);
                *(unsigned long long*)&Ps[w][qs * 16 + fr][n * 16 + fq * 4] =
                    *(unsigned long long*)tb;
            }
        }
        // PV: O^T += V^T · P   (A = V-frag, B = P row-major)
        bf16x8 pf[2][2];
#pragma unroll
        for (int qs = 0; qs < 2; qs++) {
            pf[qs][0] = *(const bf16x8*)&Ps[w][qs * 16 + fr][fq * 8];
            pf[qs][1] = *(const bf16x8*)&Ps[w][qs * 16 + fr][32 + fq * 8];
        }
#pragma unroll
        for (int dt = 0; dt < 4; dt++) {
            bf16x8 vf0 = *(const bf16x8*)&Vs[0][dt * 16 + fr][fq * 8];
            bf16x8 vf1 = *(const bf16x8*)&Vs[1][dt * 16 + fr][fq * 8];
#pragma unroll
            for (int qs = 0; qs < 2; qs++) {
                o_acc[qs][dt] = __builtin_amdgcn_mfma_f32_16x16x32_bf16(vf0, pf[qs][0], o_acc[qs][dt], 0, 0, 0);
                o_acc[qs][dt] = __builtin_amdgcn_mfma_f32_16x16x32_bf16(vf1, pf[qs][1], o_acc[qs][dt], 0, 0, 0);
            }
        }
    }

    // epilogue: O^T C-layout row=d=dt*16+fq*4+r, col=qrow -> ao[s][h*64+d]
#pragma unroll
    for (int qs = 0; qs < 2; qs++) {
        int srow = q0 + w * 32 + qs * 16 + fr;
        if (srow < SS) {
            float inv = 1.f / l_[qs];
            bf16* dst = ao + ((size_t)(b * SS + srow) * 8 + h) * 64;
#pragma unroll
            for (int dt = 0; dt < 4; dt++) {
                __align__(8) bf16 tb[4];
#pragma unroll
                for (int r = 0; r < 4; r++)
                    tb[r] = __float2bfloat16(o_acc[qs][dt][r] * inv);
                *(unsigned long long*)(dst + dt * 16 + fq * 4) =
                    *(unsigned long long*)tb;
            }
        }
    }
}

// ---------------------------------------------------------------------------
// bf16 MFMA GEMM (m97 pattern): C[M,N] = act(A[M,K] @ W[N,K]^T + bias)
// ---------------------------------------------------------------------------
template <bool RELU, bool OUT_BF16>
__global__ __launch_bounds__(256) void k_gemm_mfma(const bf16* __restrict__ A,
                                                   const bf16* __restrict__ W,
                                                   const float* __restrict__ bias,
                                                   void* __restrict__ Cout,
                                                   int M, int N, int K) {
    __shared__ __align__(16) bf16 As[128 * 32];
    __shared__ __align__(16) bf16 Ws[128 * 32];
    int t = threadIdx.x;
    int wave = t >> 6, lane = t & 63;
    int m0 = blockIdx.x * 128, n0 = blockIdx.y * 128;
    int wm = (wave >> 1) * 64, wn = (wave & 1) * 64;
    int fr = lane & 15, fq = lane >> 4;

    f32x4 acc[4][4] = {};

    int base0 = (wave << 10) + lane * 16;
    int base1 = base0 + 4096;
    int r0 = base0 >> 6, c0 = (base0 & 63) >> 1;
    int r1 = base1 >> 6, c1 = (base1 & 63) >> 1;

    for (int k0 = 0; k0 < K; k0 += 32) {
        __syncthreads();
        __builtin_amdgcn_global_load_lds(GPTR(A + (size_t)(m0 + r0) * K + k0 + c0),
                                         LPTR((char*)As + (wave << 10)), 16, 0, 0);
        __builtin_amdgcn_global_load_lds(GPTR(A + (size_t)(m0 + r1) * K + k0 + c1),
                                         LPTR((char*)As + (wave << 10) + 4096), 16, 0, 0);
        __builtin_amdgcn_global_load_lds(GPTR(W + (size_t)(n0 + r0) * K + k0 + c0),
                                         LPTR((char*)Ws + (wave << 10)), 16, 0, 0);
        __builtin_amdgcn_global_load_lds(GPTR(W + (size_t)(n0 + r1) * K + k0 + c1),
                                         LPTR((char*)Ws + (wave << 10) + 4096), 16, 0, 0);
        __syncthreads();

        bf16x8 af[4], bfr[4];
#pragma unroll
        for (int i = 0; i < 4; i++)
            af[i] = *(const bf16x8*)(As + (wm + i * 16 + fr) * 32 + fq * 8);
#pragma unroll
        for (int i = 0; i < 4; i++)
            bfr[i] = *(const bf16x8*)(Ws + (wn + i * 16 + fr) * 32 + fq * 8);
#pragma unroll
        for (int mi = 0; mi < 4; mi++)
#pragma unroll
            for (int ni = 0; ni < 4; ni++)
                acc[mi][ni] = __builtin_amdgcn_mfma_f32_16x16x32_bf16(
                    af[mi], bfr[ni], acc[mi][ni], 0, 0, 0);
    }

    float bv[4];
#pragma unroll
    for (int ni = 0; ni < 4; ni++) bv[ni] = bias[n0 + wn + ni * 16 + fr];
#pragma unroll
    for (int mi = 0; mi < 4; mi++) {
#pragma unroll
        for (int r = 0; r < 4; r++) {
            int mg = m0 + wm + mi * 16 + fq * 4 + r;
#pragma unroll
            for (int ni = 0; ni < 4; ni++) {
                float val = acc[mi][ni][r] + bv[ni];
                if (RELU) val = fmaxf(val, 0.f);
                int ng = n0 + wn + ni * 16 + fr;
                if (OUT_BF16)
                    ((bf16*)Cout)[(size_t)mg * N + ng] = __float2bfloat16(val);
                else
                    ((float*)Cout)[(size_t)mg * N + ng] = val;
            }
        }
    }
}

// ---------------------------------------------------------------------------
// Fused residual add + LayerNorm; writes fp32 out + bf16 out16.
// ---------------------------------------------------------------------------
__global__ __launch_bounds__(128) void k_add_ln(const float* __restrict__ a,
                                                const float* __restrict__ b,
                                                const float* __restrict__ w,
                                                const float* __restrict__ bias,
                                                float* __restrict__ out,
                                                bf16* __restrict__ out16) {
    int row = blockIdx.x;
    int t = threadIdx.x;
    float4 xa = ((const float4*)(a + (size_t)row * DD))[t];
    float4 xb = ((const float4*)(b + (size_t)row * DD))[t];
    float4 vv;
    vv.x = xa.x + xb.x; vv.y = xa.y + xb.y;
    vv.z = xa.z + xb.z; vv.w = xa.w + xb.w;
    float s  = vv.x + vv.y + vv.z + vv.w;
    float sq = vv.x * vv.x + vv.y * vv.y + vv.z * vv.z + vv.w * vv.w;
#pragma unroll
    for (int off = 32; off > 0; off >>= 1) {
        s  += __shfl_down(s, off);
        sq += __shfl_down(sq, off);
    }
    __shared__ float red[4];
    if ((t & 63) == 0) { red[(t >> 6) * 2] = s; red[(t >> 6) * 2 + 1] = sq; }
    __syncthreads();
    float S1 = red[0] + red[2], S2 = red[1] + red[3];
    float mean = S1 * (1.f / DD);
    float var  = S2 * (1.f / DD) - mean * mean;
    float inv  = rsqrtf(var + 1e-5f);
    float4 wv = ((const float4*)w)[t];
    float4 bv = ((const float4*)bias)[t];
    float4 o;
    o.x = (vv.x - mean) * inv * wv.x + bv.x;
    o.y = (vv.y - mean) * inv * wv.y + bv.y;
    o.z = (vv.z - mean) * inv * wv.z + bv.z;
    o.w = (vv.w - mean) * inv * wv.w + bv.w;
    ((float4*)(out + (size_t)row * DD))[t] = o;
    bf16 h0 = __float2bfloat16(o.x), h1 = __float2bfloat16(o.y);
    bf16 h2 = __float2bfloat16(o.z), h3 = __float2bfloat16(o.w);
    ushort4 u;
    u.x = *(unsigned short*)&h0; u.y = *(unsigned short*)&h1;
    u.z = *(unsigned short*)&h2; u.w = *(unsigned short*)&h3;
    ((ushort4*)(out16 + (size_t)row * DD))[t] = u;
}

// ---------------------------------------------------------------------------
extern "C" void kernel_launch(void* const* d_in, const int* in_sizes, int n_in,
                              void* d_out, int out_size, void* d_ws, size_t ws_size,
                              hipStream_t stream) {
    const int*   x    = (const int*)d_in[0];
    const float* emb  = (const float*)d_in[1];
    const float* pe   = (const float*)d_in[2];
    const float* Wq   = (const float*)d_in[3];
    const float* Wk   = (const float*)d_in[4];
    const float* Wv   = (const float*)d_in[5];
    const float* Wo   = (const float*)d_in[6];
    const float* bo   = (const float*)d_in[7];
    const float* ln1w = (const float*)d_in[8];
    const float* ln1b = (const float*)d_in[9];
    const float* W1   = (const float*)d_in[10];
    const float* b1   = (const float*)d_in[11];
    const float* W2   = (const float*)d_in[12];
    const float* b2   = (const float*)d_in[13];
    const float* ln2w = (const float*)d_in[14];
    const float* ln2b = (const float*)d_in[15];

    float* h  = (float*)d_out;
    float* ws = (float*)d_ws;
    // Region A (NBUF floats): qk bf16 [MROWS][128] -> wo_out fp32 -> ff fp32
    bf16*  qkbuf  = (bf16*)ws;
    float* wo_out = ws;
    float* ff     = ws;
    // Region B (NBUF floats): [v bf16 MROWSx64][wqkv->vT bf16] -> f1b bf16
    bf16*  v_buf  = (bf16*)(ws + NBUF);
    bf16*  vt_buf = (bf16*)(ws + NBUF + NBUF / 2);
    bf16*  wqkv   = vt_buf;            // overlaid; dead before vT written
    bf16*  f1b    = v_buf;             // [11904][2048] spans region B
    // Region C: n1 fp32
    float* n1     = ws + 2 * NBUF;
    // Region D (NBUF/2 floats): aob -> n1b (bf16 [NROWS][512])
    bf16*  regD   = (bf16*)(ws + 3 * NBUF);
    // Region E: h16
    bf16*  h16    = regD + NBUF;
    // Weights (bf16)
    bf16*  wob16  = h16 + NBUF;
    bf16*  w1b16  = wob16 + (size_t)LL * DD * DD;
    bf16*  w2b16  = w1b16 + (size_t)LL * EXPAND * DD * DD;

    k_f2b<<<2048, 256, 0, stream>>>(Wo, wob16, LL * DD * DD);
    k_f2b<<<4096, 256, 0, stream>>>(W1, w1b16, LL * EXPAND * DD * DD);
    k_f2b<<<4096, 256, 0, stream>>>(W2, w2b16, LL * EXPAND * DD * DD);
    k_embed<<<NROWS, 128, 0, stream>>>(x, emb, pe, h, h16);

    for (int l = 0; l < LL; l++) {
        k_f2b<<<16, 256, 0, stream>>>(Wq + (size_t)l * 4096, wqkv, 4096);
        k_f2b<<<16, 256, 0, stream>>>(Wk + (size_t)l * 4096, wqkv + 4096, 4096);
        k_f2b<<<16, 256, 0, stream>>>(Wv + (size_t)l * 4096, wqkv + 8192, 4096);
        k_qkv_mfma<<<MROWS / 128, 256, 0, stream>>>(h16, wqkv, qkbuf, v_buf);
        k_vt<<<dim3(256, 12), 256, 0, stream>>>(v_buf, vt_buf);
        k_attn_mfma<<<dim3(256, 6), 256, 0, stream>>>(qkbuf, vt_buf, regD);
        k_gemm_mfma<false, false><<<dim3(NROWS / 128, DD / 128), 256, 0, stream>>>(
            regD, wob16 + (size_t)l * DD * DD, bo + (size_t)l * DD, wo_out,
            NROWS, DD, DD);
        k_add_ln<<<NROWS, 128, 0, stream>>>(wo_out, h,
            ln1w + (size_t)l * DD, ln1b + (size_t)l * DD, n1, regD /*n1b*/);
        for (int c = 0; c < 2; c++) {
            const bf16* Ain = regD + (size_t)c * 11904 * DD;
            k_gemm_mfma<true, true><<<dim3(11904 / 128, (EXPAND * DD) / 128), 256, 0, stream>>>(
                Ain, w1b16 + (size_t)l * EXPAND * DD * DD, b1 + (size_t)l * EXPAND * DD,
                f1b, 11904, EXPAND * DD, DD);
            k_gemm_mfma<false, false><<<dim3(11904 / 128, DD / 128), 256, 0, stream>>>(
                f1b, w2b16 + (size_t)l * DD * EXPAND * DD, b2 + (size_t)l * DD,
                ff + (size_t)c * 11904 * DD, 11904, DD, EXPAND * DD);
        }
        k_add_ln<<<NROWS, 128, 0, stream>>>(ff, n1,
            ln2w + (size_t)l * DD, ln2b + (size_t)l * DD, h, h16);
    }
}

// Round 5
// 1746.672 us; speedup vs baseline: 9.0814x; 1.0145x over previous
//
#include <hip/hip_runtime.h>
#include <hip/hip_bf16.h>
#include <math.h>

// Problem constants
#define BB 32
#define SS 744
#define DD 512
#define HH 8
#define HDD 64
#define LL 4
#define EXPAND 4
#define NROWS (BB * SS)            // 23808
#define MROWS (NROWS * HH)         // 190464 = 1488 * 128
#define NBUF ((size_t)NROWS * DD)  // 12,189,696 floats per [B,S,D] buffer
#define SQRT_D 22.62741699796952f
#define QSCALE 0.18033688011112042f   // 0.125 * log2(e): softmax in log2 domain

typedef __hip_bfloat16 bf16;
typedef __attribute__((ext_vector_type(8))) __bf16 bf16x8;
typedef __attribute__((ext_vector_type(4))) float f32x4;

#define GPTR(p) (const __attribute__((address_space(1))) void*)(p)
#define LPTR(p) (__attribute__((address_space(3))) void*)(p)

// ---------------------------------------------------------------------------
// Embedding + positional encoding; writes fp32 h and bf16 h16
// ---------------------------------------------------------------------------
__global__ __launch_bounds__(128) void k_embed(const int* __restrict__ x,
                                               const float* __restrict__ emb,
                                               const float* __restrict__ pe,
                                               float* __restrict__ h,
                                               bf16* __restrict__ h16) {
    int row = blockIdx.x;
    int s = row % SS;
    int tok = x[row];
    int t = threadIdx.x;
    float4 e = ((const float4*)(emb + (size_t)tok * DD))[t];
    float4 p = ((const float4*)(pe + (size_t)s * DD))[t];
    float4 o;
    o.x = e.x * SQRT_D + p.x;
    o.y = e.y * SQRT_D + p.y;
    o.z = e.z * SQRT_D + p.z;
    o.w = e.w * SQRT_D + p.w;
    ((float4*)(h + (size_t)row * DD))[t] = o;
    bf16 b0 = __float2bfloat16(o.x), b1 = __float2bfloat16(o.y);
    bf16 b2 = __float2bfloat16(o.z), b3 = __float2bfloat16(o.w);
    ushort4 u;
    u.x = *(unsigned short*)&b0; u.y = *(unsigned short*)&b1;
    u.z = *(unsigned short*)&b2; u.w = *(unsigned short*)&b3;
    ((ushort4*)(h16 + (size_t)row * DD))[t] = u;
}

// ---------------------------------------------------------------------------
// fp32 -> bf16 conversion (grid-stride)
// ---------------------------------------------------------------------------
__global__ __launch_bounds__(256) void k_f2b(const float* __restrict__ in,
                                             bf16* __restrict__ out, int n) {
    for (int i = blockIdx.x * 256 + threadIdx.x; i < n; i += gridDim.x * 256)
        out[i] = __float2bfloat16(in[i]);
}

// ---------------------------------------------------------------------------
// QKV projection as one MFMA GEMM: A = h16 as [(b,s,h)][64], W = [192][64]
// q columns (0-63) pre-scaled by 0.125*log2(e) so attention softmax can use
// exp2 with no in-loop scaling.
// ---------------------------------------------------------------------------
__global__ __launch_bounds__(256) void k_qkv_mfma(const bf16* __restrict__ A,
                                                  const bf16* __restrict__ Wqkv,
                                                  bf16* __restrict__ qk,
                                                  bf16* __restrict__ v) {
    __shared__ __align__(16) bf16 As[2][128][32];
    __shared__ __align__(16) bf16 Ws[2][192][32];
    int t = threadIdx.x;
    int w = t >> 6, lane = t & 63;
    int fr = lane & 15, fq = lane >> 4;
    int m0 = blockIdx.x * 128;
    int wm = (w >> 1) * 64;        // row half
    int wc = (w & 1) * 96;         // col half
    int lr = lane >> 2, lc8 = (lane & 3) * 8;

#pragma unroll
    for (int kc = 0; kc < 2; kc++)
#pragma unroll
        for (int i = 0; i < 2; i++) {
            int rb = w * 32 + i * 16;
            __builtin_amdgcn_global_load_lds(
                GPTR(A + (size_t)(m0 + rb + lr) * 64 + kc * 32 + lc8),
                LPTR(&As[kc][rb][0]), 16, 0, 0);
        }
#pragma unroll
    for (int kc = 0; kc < 2; kc++)
#pragma unroll
        for (int i = 0; i < 3; i++) {
            int rb = w * 48 + i * 16;
            __builtin_amdgcn_global_load_lds(
                GPTR(Wqkv + (size_t)(rb + lr) * 64 + kc * 32 + lc8),
                LPTR(&Ws[kc][rb][0]), 16, 0, 0);
        }
    __syncthreads();

    bf16x8 af[2][4], bw[2][6];
#pragma unroll
    for (int kc = 0; kc < 2; kc++) {
#pragma unroll
        for (int mi = 0; mi < 4; mi++)
            af[kc][mi] = *(const bf16x8*)&As[kc][wm + mi * 16 + fr][fq * 8];
#pragma unroll
        for (int ni = 0; ni < 6; ni++)
            bw[kc][ni] = *(const bf16x8*)&Ws[kc][wc + ni * 16 + fr][fq * 8];
    }
    f32x4 acc[4][6] = {};
#pragma unroll
    for (int mi = 0; mi < 4; mi++)
#pragma unroll
        for (int ni = 0; ni < 6; ni++) {
            acc[mi][ni] = __builtin_amdgcn_mfma_f32_16x16x32_bf16(af[0][mi], bw[0][ni], acc[mi][ni], 0, 0, 0);
            acc[mi][ni] = __builtin_amdgcn_mfma_f32_16x16x32_bf16(af[1][mi], bw[1][ni], acc[mi][ni], 0, 0, 0);
        }

#pragma unroll
    for (int mi = 0; mi < 4; mi++)
#pragma unroll
        for (int r = 0; r < 4; r++) {
            size_t mg = m0 + wm + mi * 16 + fq * 4 + r;
#pragma unroll
            for (int ni = 0; ni < 6; ni++) {
                int col = wc + ni * 16 + fr;
                float fv = acc[mi][ni][r];
                if (col < 64) fv *= QSCALE;
                bf16 val = __float2bfloat16(fv);
                if (col < 128) qk[mg * 128 + col] = val;
                else           v[mg * 64 + (col - 128)] = val;
            }
        }
}

// ---------------------------------------------------------------------------
// V transpose: v [(b,s,h)][64] -> vt [bh*64 + d][744]. grid (256, 12).
// ---------------------------------------------------------------------------
__global__ __launch_bounds__(256) void k_vt(const bf16* __restrict__ v,
                                            bf16* __restrict__ vt) {
    int bh = blockIdx.x, st = blockIdx.y;
    int b = bh >> 3, h = bh & 7;
    int t = threadIdx.x;
    __shared__ bf16 Ls[64][72];
    int s0 = st * 64;
    for (int j = t; j < 512; j += 256) {
        int si = j >> 3, e8 = (j & 7) * 8;
        int s = s0 + si; if (s > SS - 1) s = SS - 1;
        bf16x8 val = *(const bf16x8*)(v + ((size_t)(b * SS + s) * 8 + h) * 64 + e8);
        *(bf16x8*)&Ls[si][e8] = val;
    }
    __syncthreads();
    for (int j = t; j < 512; j += 256) {
        int d = j >> 3, s8 = (j & 7) * 8;
        if (s0 + s8 < SS) {
            __align__(16) bf16 tmp[8];
#pragma unroll
            for (int i = 0; i < 8; i++) tmp[i] = Ls[s8 + i][d];
            *(bf16x8*)(vt + ((size_t)bh * 64 + d) * SS + s0 + s8) = *(bf16x8*)tmp;
        }
    }
}

// ---------------------------------------------------------------------------
// Flash MFMA attention, S^T orientation, log2-domain softmax.
// grid (256 bh, 6 q-tiles of 128). Per block: 4 waves x 32 q-rows.
// P stored K-style [kc][qrow][32] so PV B-frag reads are dense-contiguous.
// Mask/clamp only on the last key-tile (wave-uniform branch).
// ---------------------------------------------------------------------------
__global__ __launch_bounds__(256) void k_attn_mfma(const bf16* __restrict__ qk,
                                                   const bf16* __restrict__ vt,
                                                   bf16* __restrict__ ao) {
    int bh = blockIdx.x, qt = blockIdx.y;
    int b = bh >> 3, h = bh & 7;
    int t = threadIdx.x;
    int w = t >> 6, lane = t & 63;
    int fr = lane & 15, fq = lane >> 4;
    int lr = lane >> 2, lc8 = (lane & 3) * 8;
    int q0 = qt * 128;

    __shared__ __align__(16) bf16 Ks[2][64][32];
    __shared__ __align__(16) bf16 Vs[2][64][32];
    __shared__ __align__(16) bf16 Ps[4][2][32][32];   // [wave][kc][qrow][key%32]

    // Q fragments direct from global (once per block): B-frag Q[qrow][e]
    bf16x8 qf[2][2];
#pragma unroll
    for (int qs = 0; qs < 2; qs++) {
        int row = q0 + w * 32 + qs * 16 + fr;
        if (row > SS - 1) row = SS - 1;
        size_t gb = ((size_t)(b * SS + row) * 8 + h) * 128;
        qf[qs][0] = *(const bf16x8*)(qk + gb + fq * 8);
        qf[qs][1] = *(const bf16x8*)(qk + gb + 32 + fq * 8);
    }

    // staging pointers (unclamped, valid for kt 0..10)
    const bf16* kp = qk + (((size_t)b * SS + w * 16 + lr) * 8 + h) * 128 + 64 + lc8;
    const bf16* vp = vt + ((size_t)bh * 64 + w * 16 + lr) * SS + lc8;

    f32x4 o_acc[2][4] = {};                 // [qset][d-tile]
    float m_[2] = {-1e30f, -1e30f};
    float l_[2] = {0.f, 0.f};

    for (int kt = 0; kt < 12; kt++) {
        __syncthreads();   // all waves done with Ks/Vs before restage
        if (kt < 11) {
            const bf16* kpp = kp + (size_t)kt * 65536;   // 64 rows * 8h * 128
            const bf16* vpp = vp + kt * 64;
#pragma unroll
            for (int kc = 0; kc < 2; kc++) {
                __builtin_amdgcn_global_load_lds(GPTR(kpp + kc * 32),
                                                 LPTR(&Ks[kc][w * 16][0]), 16, 0, 0);
                __builtin_amdgcn_global_load_lds(GPTR(vpp + kc * 32),
                                                 LPTR(&Vs[kc][w * 16][0]), 16, 0, 0);
            }
        } else {
            int krow = 704 + w * 16 + lr; if (krow > SS - 1) krow = SS - 1;
            size_t gbk = ((size_t)(b * SS + krow) * 8 + h) * 128 + 64;
            size_t gbv = ((size_t)bh * 64 + w * 16 + lr) * SS;
#pragma unroll
            for (int kc = 0; kc < 2; kc++) {
                __builtin_amdgcn_global_load_lds(GPTR(qk + gbk + kc * 32 + lc8),
                                                 LPTR(&Ks[kc][w * 16][0]), 16, 0, 0);
                int key = 704 + kc * 32 + lc8; if (key > SS - 8) key = SS - 8;
                __builtin_amdgcn_global_load_lds(GPTR(vt + gbv + key),
                                                 LPTR(&Vs[kc][w * 16][0]), 16, 0, 0);
            }
        }
        __syncthreads();

        // K fragments: A[m=key][k=e], shared across both q-sets
        bf16x8 kf[4][2];
#pragma unroll
        for (int n = 0; n < 4; n++) {
            kf[n][0] = *(const bf16x8*)&Ks[0][n * 16 + fr][fq * 8];
            kf[n][1] = *(const bf16x8*)&Ks[1][n * 16 + fr][fq * 8];
        }

#pragma unroll
        for (int qs = 0; qs < 2; qs++) {
            // S^T tiles (log2-domain scores; Q pre-scaled)
            f32x4 st[4] = {};
#pragma unroll
            for (int n = 0; n < 4; n++) {
                st[n] = __builtin_amdgcn_mfma_f32_16x16x32_bf16(kf[n][0], qf[qs][0], st[n], 0, 0, 0);
                st[n] = __builtin_amdgcn_mfma_f32_16x16x32_bf16(kf[n][1], qf[qs][1], st[n], 0, 0, 0);
            }
            if (kt == 11) {   // mask invalid keys (uniform branch, last tile only)
#pragma unroll
                for (int n = 0; n < 4; n++) {
                    int kb = 704 + n * 16 + fq * 4;
#pragma unroll
                    for (int r = 0; r < 4; r++)
                        if (kb + r >= SS) st[n][r] = -1e30f;
                }
            }
            // online softmax: all 16 values in this lane share one qrow
            float mx = -1e30f;
#pragma unroll
            for (int n = 0; n < 4; n++)
#pragma unroll
                for (int r = 0; r < 4; r++) mx = fmaxf(mx, st[n][r]);
            mx = fmaxf(mx, __shfl_xor(mx, 16));
            mx = fmaxf(mx, __shfl_xor(mx, 32));
            float mnew = fmaxf(m_[qs], mx);
            float alpha = exp2f(m_[qs] - mnew);
            m_[qs] = mnew;
            float ls = 0.f;
#pragma unroll
            for (int n = 0; n < 4; n++)
#pragma unroll
                for (int r = 0; r < 4; r++) {
                    float p = exp2f(st[n][r] - mnew);
                    st[n][r] = p;
                    ls += p;
                }
            ls += __shfl_xor(ls, 16);
            ls += __shfl_xor(ls, 32);
            l_[qs] = l_[qs] * alpha + ls;
#pragma unroll
            for (int dt = 0; dt < 4; dt++)
#pragma unroll
                for (int r = 0; r < 4; r++) o_acc[qs][dt][r] *= alpha;
            // store P K-style: row=qrow, col=key%32, plane=key/32 (8B writes)
#pragma unroll
            for (int n = 0; n < 4; n++) {
                __align__(8) bf16 tb[4];
#pragma unroll
                for (int r = 0; r < 4; r++) tb[r] = __float2bfloat16(st[n][r]);
                *(unsigned long long*)&Ps[w][n >> 1][qs * 16 + fr][(n & 1) * 16 + fq * 4] =
                    *(unsigned long long*)tb;
            }
        }
        // PV: O^T += V^T · P  (A = V-frag, B = P, dense-contiguous reads)
        bf16x8 pf[2][2];
#pragma unroll
        for (int qs = 0; qs < 2; qs++) {
            pf[qs][0] = *(const bf16x8*)&Ps[w][0][qs * 16 + fr][fq * 8];
            pf[qs][1] = *(const bf16x8*)&Ps[w][1][qs * 16 + fr][fq * 8];
        }
#pragma unroll
        for (int dt = 0; dt < 4; dt++) {
            bf16x8 vf0 = *(const bf16x8*)&Vs[0][dt * 16 + fr][fq * 8];
            bf16x8 vf1 = *(const bf16x8*)&Vs[1][dt * 16 + fr][fq * 8];
#pragma unroll
            for (int qs = 0; qs < 2; qs++) {
                o_acc[qs][dt] = __builtin_amdgcn_mfma_f32_16x16x32_bf16(vf0, pf[qs][0], o_acc[qs][dt], 0, 0, 0);
                o_acc[qs][dt] = __builtin_amdgcn_mfma_f32_16x16x32_bf16(vf1, pf[qs][1], o_acc[qs][dt], 0, 0, 0);
            }
        }
    }

    // epilogue: O^T C-layout row=d=dt*16+fq*4+r, col=qrow -> ao[s][h*64+d]
#pragma unroll
    for (int qs = 0; qs < 2; qs++) {
        int srow = q0 + w * 32 + qs * 16 + fr;
        if (srow < SS) {
            float inv = 1.f / l_[qs];
            bf16* dst = ao + ((size_t)(b * SS + srow) * 8 + h) * 64;
#pragma unroll
            for (int dt = 0; dt < 4; dt++) {
                __align__(8) bf16 tb[4];
#pragma unroll
                for (int r = 0; r < 4; r++)
                    tb[r] = __float2bfloat16(o_acc[qs][dt][r] * inv);
                *(unsigned long long*)(dst + dt * 16 + fq * 4) =
                    *(unsigned long long*)tb;
            }
        }
    }
}

// ---------------------------------------------------------------------------
// bf16 MFMA GEMM (m97 pattern): C[M,N] = act(A[M,K] @ W[N,K]^T + bias)
// ---------------------------------------------------------------------------
template <bool RELU, bool OUT_BF16>
__global__ __launch_bounds__(256) void k_gemm_mfma(const bf16* __restrict__ A,
                                                   const bf16* __restrict__ W,
                                                   const float* __restrict__ bias,
                                                   void* __restrict__ Cout,
                                                   int M, int N, int K) {
    __shared__ __align__(16) bf16 As[128 * 32];
    __shared__ __align__(16) bf16 Ws[128 * 32];
    int t = threadIdx.x;
    int wave = t >> 6, lane = t & 63;
    int m0 = blockIdx.x * 128, n0 = blockIdx.y * 128;
    int wm = (wave >> 1) * 64, wn = (wave & 1) * 64;
    int fr = lane & 15, fq = lane >> 4;

    f32x4 acc[4][4] = {};

    int base0 = (wave << 10) + lane * 16;
    int base1 = base0 + 4096;
    int r0 = base0 >> 6, c0 = (base0 & 63) >> 1;
    int r1 = base1 >> 6, c1 = (base1 & 63) >> 1;

    for (int k0 = 0; k0 < K; k0 += 32) {
        __syncthreads();
        __builtin_amdgcn_global_load_lds(GPTR(A + (size_t)(m0 + r0) * K + k0 + c0),
                                         LPTR((char*)As + (wave << 10)), 16, 0, 0);
        __builtin_amdgcn_global_load_lds(GPTR(A + (size_t)(m0 + r1) * K + k0 + c1),
                                         LPTR((char*)As + (wave << 10) + 4096), 16, 0, 0);
        __builtin_amdgcn_global_load_lds(GPTR(W + (size_t)(n0 + r0) * K + k0 + c0),
                                         LPTR((char*)Ws + (wave << 10)), 16, 0, 0);
        __builtin_amdgcn_global_load_lds(GPTR(W + (size_t)(n0 + r1) * K + k0 + c1),
                                         LPTR((char*)Ws + (wave << 10) + 4096), 16, 0, 0);
        __syncthreads();

        bf16x8 af[4], bfr[4];
#pragma unroll
        for (int i = 0; i < 4; i++)
            af[i] = *(const bf16x8*)(As + (wm + i * 16 + fr) * 32 + fq * 8);
#pragma unroll
        for (int i = 0; i < 4; i++)
            bfr[i] = *(const bf16x8*)(Ws + (wn + i * 16 + fr) * 32 + fq * 8);
#pragma unroll
        for (int mi = 0; mi < 4; mi++)
#pragma unroll
            for (int ni = 0; ni < 4; ni++)
                acc[mi][ni] = __builtin_amdgcn_mfma_f32_16x16x32_bf16(
                    af[mi], bfr[ni], acc[mi][ni], 0, 0, 0);
    }

    float bv[4];
#pragma unroll
    for (int ni = 0; ni < 4; ni++) bv[ni] = bias[n0 + wn + ni * 16 + fr];
#pragma unroll
    for (int mi = 0; mi < 4; mi++) {
#pragma unroll
        for (int r = 0; r < 4; r++) {
            int mg = m0 + wm + mi * 16 + fq * 4 + r;
#pragma unroll
            for (int ni = 0; ni < 4; ni++) {
                float val = acc[mi][ni][r] + bv[ni];
                if (RELU) val = fmaxf(val, 0.f);
                int ng = n0 + wn + ni * 16 + fr;
                if (OUT_BF16)
                    ((bf16*)Cout)[(size_t)mg * N + ng] = __float2bfloat16(val);
                else
                    ((float*)Cout)[(size_t)mg * N + ng] = val;
            }
        }
    }
}

// ---------------------------------------------------------------------------
// Fused residual add + LayerNorm.
// BRES16: residual `bres` is bf16 (else fp32). WF32: also write fp32 out.
// Always writes bf16 out16.
// ---------------------------------------------------------------------------
template <bool BRES16, bool WF32>
__global__ __launch_bounds__(128) void k_add_ln(const float* __restrict__ a,
                                                const void* __restrict__ bres,
                                                const float* __restrict__ w,
                                                const float* __restrict__ bias,
                                                float* out,
                                                bf16* __restrict__ out16) {
    int row = blockIdx.x;
    int t = threadIdx.x;
    float4 xa = ((const float4*)(a + (size_t)row * DD))[t];
    float4 xb;
    if (BRES16) {
        ushort4 ub = ((const ushort4*)((const bf16*)bres + (size_t)row * DD))[t];
        xb.x = __bfloat162float(*(bf16*)&ub.x);
        xb.y = __bfloat162float(*(bf16*)&ub.y);
        xb.z = __bfloat162float(*(bf16*)&ub.z);
        xb.w = __bfloat162float(*(bf16*)&ub.w);
    } else {
        xb = ((const float4*)((const float*)bres + (size_t)row * DD))[t];
    }
    float4 vv;
    vv.x = xa.x + xb.x; vv.y = xa.y + xb.y;
    vv.z = xa.z + xb.z; vv.w = xa.w + xb.w;
    float s  = vv.x + vv.y + vv.z + vv.w;
    float sq = vv.x * vv.x + vv.y * vv.y + vv.z * vv.z + vv.w * vv.w;
#pragma unroll
    for (int off = 32; off > 0; off >>= 1) {
        s  += __shfl_down(s, off);
        sq += __shfl_down(sq, off);
    }
    __shared__ float red[4];
    if ((t & 63) == 0) { red[(t >> 6) * 2] = s; red[(t >> 6) * 2 + 1] = sq; }
    __syncthreads();
    float S1 = red[0] + red[2], S2 = red[1] + red[3];
    float mean = S1 * (1.f / DD);
    float var  = S2 * (1.f / DD) - mean * mean;
    float inv  = rsqrtf(var + 1e-5f);
    float4 wv = ((const float4*)w)[t];
    float4 bv = ((const float4*)bias)[t];
    float4 o;
    o.x = (vv.x - mean) * inv * wv.x + bv.x;
    o.y = (vv.y - mean) * inv * wv.y + bv.y;
    o.z = (vv.z - mean) * inv * wv.z + bv.z;
    o.w = (vv.w - mean) * inv * wv.w + bv.w;
    if (WF32)
        ((float4*)(out + (size_t)row * DD))[t] = o;
    bf16 h0 = __float2bfloat16(o.x), h1 = __float2bfloat16(o.y);
    bf16 h2 = __float2bfloat16(o.z), h3 = __float2bfloat16(o.w);
    ushort4 u;
    u.x = *(unsigned short*)&h0; u.y = *(unsigned short*)&h1;
    u.z = *(unsigned short*)&h2; u.w = *(unsigned short*)&h3;
    ((ushort4*)(out16 + (size_t)row * DD))[t] = u;
}

// ---------------------------------------------------------------------------
extern "C" void kernel_launch(void* const* d_in, const int* in_sizes, int n_in,
                              void* d_out, int out_size, void* d_ws, size_t ws_size,
                              hipStream_t stream) {
    const int*   x    = (const int*)d_in[0];
    const float* emb  = (const float*)d_in[1];
    const float* pe   = (const float*)d_in[2];
    const float* Wq   = (const float*)d_in[3];
    const float* Wk   = (const float*)d_in[4];
    const float* Wv   = (const float*)d_in[5];
    const float* Wo   = (const float*)d_in[6];
    const float* bo   = (const float*)d_in[7];
    const float* ln1w = (const float*)d_in[8];
    const float* ln1b = (const float*)d_in[9];
    const float* W1   = (const float*)d_in[10];
    const float* b1   = (const float*)d_in[11];
    const float* W2   = (const float*)d_in[12];
    const float* b2   = (const float*)d_in[13];
    const float* ln2w = (const float*)d_in[14];
    const float* ln2b = (const float*)d_in[15];

    float* h  = (float*)d_out;
    float* ws = (float*)d_ws;
    // Region A [0, NBUF): qk bf16 [MROWS][128] -> wo_out fp32 -> ff fp32
    bf16*  qkbuf  = (bf16*)ws;
    float* wo_out = ws;
    float* ff     = ws;
    // Region B+C [NBUF, 3*NBUF): v/vt/wqkv (dead after attn) -> f1b bf16 [23808][2048]
    bf16*  v_buf  = (bf16*)(ws + NBUF);
    bf16*  vt_buf = (bf16*)(ws + NBUF + NBUF / 2);
    bf16*  wqkv   = vt_buf;            // overlaid; dead before vT written
    bf16*  f1b    = (bf16*)(ws + NBUF);
    // Region D [3*NBUF, 3.5*NBUF): aob -> n1b (bf16 [NROWS][512])
    bf16*  regD   = (bf16*)(ws + 3 * NBUF);
    // Region E [3.5*NBUF, 4*NBUF): h16
    bf16*  h16    = regD + NBUF;
    // Weights (bf16)
    bf16*  wob16  = h16 + NBUF;
    bf16*  w1b16  = wob16 + (size_t)LL * DD * DD;
    bf16*  w2b16  = w1b16 + (size_t)LL * EXPAND * DD * DD;

    k_f2b<<<2048, 256, 0, stream>>>(Wo, wob16, LL * DD * DD);
    k_f2b<<<4096, 256, 0, stream>>>(W1, w1b16, LL * EXPAND * DD * DD);
    k_f2b<<<4096, 256, 0, stream>>>(W2, w2b16, LL * EXPAND * DD * DD);
    k_embed<<<NROWS, 128, 0, stream>>>(x, emb, pe, h, h16);

    for (int l = 0; l < LL; l++) {
        k_f2b<<<16, 256, 0, stream>>>(Wq + (size_t)l * 4096, wqkv, 4096);
        k_f2b<<<16, 256, 0, stream>>>(Wk + (size_t)l * 4096, wqkv + 4096, 4096);
        k_f2b<<<16, 256, 0, stream>>>(Wv + (size_t)l * 4096, wqkv + 8192, 4096);
        k_qkv_mfma<<<MROWS / 128, 256, 0, stream>>>(h16, wqkv, qkbuf, v_buf);
        k_vt<<<dim3(256, 12), 256, 0, stream>>>(v_buf, vt_buf);
        k_attn_mfma<<<dim3(256, 6), 256, 0, stream>>>(qkbuf, vt_buf, regD);
        k_gemm_mfma<false, false><<<dim3(NROWS / 128, DD / 128), 256, 0, stream>>>(
            regD, wob16 + (size_t)l * DD * DD, bo + (size_t)l * DD, wo_out,
            NROWS, DD, DD);
        // n1 kept only as bf16 (regD); frees region C for full-size f1b
        k_add_ln<false, false><<<NROWS, 128, 0, stream>>>(wo_out, h,
            ln1w + (size_t)l * DD, ln1b + (size_t)l * DD, nullptr, regD);
        k_gemm_mfma<true, true><<<dim3(NROWS / 128, (EXPAND * DD) / 128), 256, 0, stream>>>(
            regD, w1b16 + (size_t)l * EXPAND * DD * DD, b1 + (size_t)l * EXPAND * DD,
            f1b, NROWS, EXPAND * DD, DD);
        k_gemm_mfma<false, false><<<dim3(NROWS / 128, DD / 128), 256, 0, stream>>>(
            f1b, w2b16 + (size_t)l * DD * EXPAND * DD, b2 + (size_t)l * DD,
            ff, NROWS, DD, EXPAND * DD);
        k_add_ln<true, true><<<NROWS, 128, 0, stream>>>(ff, regD,
            ln2w + (size_t)l * DD, ln2b + (size_t)l * DD, h, h16);
    }
}

// Round 6
// 1584.009 us; speedup vs baseline: 10.0139x; 1.1027x over previous
//
#include <hip/hip_runtime.h>
#include <hip/hip_bf16.h>
#include <math.h>

// Problem constants
#define BB 32
#define SS 744
#define DD 512
#define HH 8
#define HDD 64
#define LL 4
#define EXPAND 4
#define NROWS (BB * SS)            // 23808
#define MROWS (NROWS * HH)         // 190464 = 1488 * 128
#define NBUF ((size_t)NROWS * DD)  // 12,189,696 floats per [B,S,D] buffer
#define SQRT_D 22.62741699796952f
#define QSCALE 0.18033688011112042f   // 0.125 * log2(e): softmax in log2 domain

typedef __hip_bfloat16 bf16;
typedef __attribute__((ext_vector_type(8))) __bf16 bf16x8;
typedef __attribute__((ext_vector_type(4))) float f32x4;

#define GPTR(p) (const __attribute__((address_space(1))) void*)(p)
#define LPTR(p) (__attribute__((address_space(3))) void*)(p)

// XOR-swizzle: lane l stages global chunk ((l&3)^((l>>3)&3)) of local row l>>2
// into contiguous LDS slot l. Frag read of (row fr, chunk fq) is then at
// physical chunk fq^((fr>>1)&3): bank-starts span 8 groups -> 2-way (free).

// ---------------------------------------------------------------------------
// Embedding + positional encoding; writes fp32 h and bf16 h16
// ---------------------------------------------------------------------------
__global__ __launch_bounds__(128) void k_embed(const int* __restrict__ x,
                                               const float* __restrict__ emb,
                                               const float* __restrict__ pe,
                                               float* __restrict__ h,
                                               bf16* __restrict__ h16) {
    int row = blockIdx.x;
    int s = row % SS;
    int tok = x[row];
    int t = threadIdx.x;
    float4 e = ((const float4*)(emb + (size_t)tok * DD))[t];
    float4 p = ((const float4*)(pe + (size_t)s * DD))[t];
    float4 o;
    o.x = e.x * SQRT_D + p.x;
    o.y = e.y * SQRT_D + p.y;
    o.z = e.z * SQRT_D + p.z;
    o.w = e.w * SQRT_D + p.w;
    ((float4*)(h + (size_t)row * DD))[t] = o;
    bf16 b0 = __float2bfloat16(o.x), b1 = __float2bfloat16(o.y);
    bf16 b2 = __float2bfloat16(o.z), b3 = __float2bfloat16(o.w);
    ushort4 u;
    u.x = *(unsigned short*)&b0; u.y = *(unsigned short*)&b1;
    u.z = *(unsigned short*)&b2; u.w = *(unsigned short*)&b3;
    ((ushort4*)(h16 + (size_t)row * DD))[t] = u;
}

// ---------------------------------------------------------------------------
// fp32 -> bf16 conversion (grid-stride)
// ---------------------------------------------------------------------------
__global__ __launch_bounds__(256) void k_f2b(const float* __restrict__ in,
                                             bf16* __restrict__ out, int n) {
    for (int i = blockIdx.x * 256 + threadIdx.x; i < n; i += gridDim.x * 256)
        out[i] = __float2bfloat16(in[i]);
}

// ---------------------------------------------------------------------------
// QKV projection as one MFMA GEMM: A = h16 as [(b,s,h)][64], W = [192][64]
// q columns (0-63) pre-scaled by 0.125*log2(e).
// ---------------------------------------------------------------------------
__global__ __launch_bounds__(256) void k_qkv_mfma(const bf16* __restrict__ A,
                                                  const bf16* __restrict__ Wqkv,
                                                  bf16* __restrict__ qk,
                                                  bf16* __restrict__ v) {
    __shared__ __align__(16) bf16 As[2][128][32];
    __shared__ __align__(16) bf16 Ws[2][192][32];
    int t = threadIdx.x;
    int w = t >> 6, lane = t & 63;
    int fr = lane & 15, fq = lane >> 4;
    int m0 = blockIdx.x * 128;
    int wm = (w >> 1) * 64;        // row half
    int wc = (w & 1) * 96;         // col half
    int lr = lane >> 2;
    int csw = ((lane & 3) ^ ((lane >> 3) & 3)) * 8;   // swizzled global chunk
    int swz8 = (fq ^ ((fr >> 1) & 3)) * 8;            // swizzled frag-read col

#pragma unroll
    for (int kc = 0; kc < 2; kc++)
#pragma unroll
        for (int i = 0; i < 2; i++) {
            int rb = w * 32 + i * 16;
            __builtin_amdgcn_global_load_lds(
                GPTR(A + (size_t)(m0 + rb + lr) * 64 + kc * 32 + csw),
                LPTR(&As[kc][rb][0]), 16, 0, 0);
        }
#pragma unroll
    for (int kc = 0; kc < 2; kc++)
#pragma unroll
        for (int i = 0; i < 3; i++) {
            int rb = w * 48 + i * 16;
            __builtin_amdgcn_global_load_lds(
                GPTR(Wqkv + (size_t)(rb + lr) * 64 + kc * 32 + csw),
                LPTR(&Ws[kc][rb][0]), 16, 0, 0);
        }
    __syncthreads();

    bf16x8 af[2][4], bw[2][6];
#pragma unroll
    for (int kc = 0; kc < 2; kc++) {
#pragma unroll
        for (int mi = 0; mi < 4; mi++)
            af[kc][mi] = *(const bf16x8*)&As[kc][wm + mi * 16 + fr][swz8];
#pragma unroll
        for (int ni = 0; ni < 6; ni++)
            bw[kc][ni] = *(const bf16x8*)&Ws[kc][wc + ni * 16 + fr][swz8];
    }
    f32x4 acc[4][6] = {};
#pragma unroll
    for (int mi = 0; mi < 4; mi++)
#pragma unroll
        for (int ni = 0; ni < 6; ni++) {
            acc[mi][ni] = __builtin_amdgcn_mfma_f32_16x16x32_bf16(af[0][mi], bw[0][ni], acc[mi][ni], 0, 0, 0);
            acc[mi][ni] = __builtin_amdgcn_mfma_f32_16x16x32_bf16(af[1][mi], bw[1][ni], acc[mi][ni], 0, 0, 0);
        }

#pragma unroll
    for (int mi = 0; mi < 4; mi++)
#pragma unroll
        for (int r = 0; r < 4; r++) {
            size_t mg = m0 + wm + mi * 16 + fq * 4 + r;
#pragma unroll
            for (int ni = 0; ni < 6; ni++) {
                int col = wc + ni * 16 + fr;
                float fv = acc[mi][ni][r];
                if (col < 64) fv *= QSCALE;
                bf16 val = __float2bfloat16(fv);
                if (col < 128) qk[mg * 128 + col] = val;
                else           v[mg * 64 + (col - 128)] = val;
            }
        }
}

// ---------------------------------------------------------------------------
// V transpose: v [(b,s,h)][64] -> vt [bh*64 + d][744]. grid (256, 12).
// ---------------------------------------------------------------------------
__global__ __launch_bounds__(256) void k_vt(const bf16* __restrict__ v,
                                            bf16* __restrict__ vt) {
    int bh = blockIdx.x, st = blockIdx.y;
    int b = bh >> 3, h = bh & 7;
    int t = threadIdx.x;
    __shared__ bf16 Ls[64][72];
    int s0 = st * 64;
    for (int j = t; j < 512; j += 256) {
        int si = j >> 3, e8 = (j & 7) * 8;
        int s = s0 + si; if (s > SS - 1) s = SS - 1;
        bf16x8 val = *(const bf16x8*)(v + ((size_t)(b * SS + s) * 8 + h) * 64 + e8);
        *(bf16x8*)&Ls[si][e8] = val;
    }
    __syncthreads();
    for (int j = t; j < 512; j += 256) {
        int d = j >> 3, s8 = (j & 7) * 8;
        if (s0 + s8 < SS) {
            __align__(16) bf16 tmp[8];
#pragma unroll
            for (int i = 0; i < 8; i++) tmp[i] = Ls[s8 + i][d];
            *(bf16x8*)(vt + ((size_t)bh * 64 + d) * SS + s0 + s8) = *(bf16x8*)tmp;
        }
    }
}

// ---------------------------------------------------------------------------
// Flash MFMA attention, S^T orientation, log2-domain softmax, swizzled LDS.
// grid (256 bh, 6 q-tiles of 128). Per block: 4 waves x 32 q-rows.
// ---------------------------------------------------------------------------
__global__ __launch_bounds__(256) void k_attn_mfma(const bf16* __restrict__ qk,
                                                   const bf16* __restrict__ vt,
                                                   bf16* __restrict__ ao) {
    int bh = blockIdx.x, qt = blockIdx.y;
    int b = bh >> 3, h = bh & 7;
    int t = threadIdx.x;
    int w = t >> 6, lane = t & 63;
    int fr = lane & 15, fq = lane >> 4;
    int lr = lane >> 2;
    int csw = ((lane & 3) ^ ((lane >> 3) & 3)) * 8;   // swizzled global chunk
    int swz8 = (fq ^ ((fr >> 1) & 3)) * 8;            // swizzled frag-read col
    int q0 = qt * 128;

    __shared__ __align__(16) bf16 Ks[2][64][32];
    __shared__ __align__(16) bf16 Vs[2][64][32];
    __shared__ __align__(16) bf16 Ps[4][2][32][40];   // padded planes: rows 80B

    // Q fragments direct from global (once per block): B-frag Q[qrow][e]
    bf16x8 qf[2][2];
#pragma unroll
    for (int qs = 0; qs < 2; qs++) {
        int row = q0 + w * 32 + qs * 16 + fr;
        if (row > SS - 1) row = SS - 1;
        size_t gb = ((size_t)(b * SS + row) * 8 + h) * 128;
        qf[qs][0] = *(const bf16x8*)(qk + gb + fq * 8);
        qf[qs][1] = *(const bf16x8*)(qk + gb + 32 + fq * 8);
    }

    f32x4 o_acc[2][4] = {};                 // [qset][d-tile]
    float m_[2] = {-1e30f, -1e30f};
    float l_[2] = {0.f, 0.f};

    for (int kt = 0; kt < 12; kt++) {
        int k0 = kt * 64;
        __syncthreads();   // all waves done with Ks/Vs before restage
        {
            int krow = k0 + w * 16 + lr; if (krow > SS - 1) krow = SS - 1;
            size_t kgb = ((size_t)(b * SS + krow) * 8 + h) * 128 + 64;
            size_t vgb = ((size_t)bh * 64 + w * 16 + lr) * SS;
#pragma unroll
            for (int p = 0; p < 2; p++) {
                __builtin_amdgcn_global_load_lds(GPTR(qk + kgb + p * 32 + csw),
                                                 LPTR(&Ks[p][w * 16][0]), 16, 0, 0);
                int key = k0 + p * 32 + csw; if (key > SS - 8) key = SS - 8;
                __builtin_amdgcn_global_load_lds(GPTR(vt + vgb + key),
                                                 LPTR(&Vs[p][w * 16][0]), 16, 0, 0);
            }
        }
        __syncthreads();

        // K fragments: A[m=key][k=e], shared across both q-sets
        bf16x8 kf[4][2];
#pragma unroll
        for (int n = 0; n < 4; n++) {
            kf[n][0] = *(const bf16x8*)&Ks[0][n * 16 + fr][swz8];
            kf[n][1] = *(const bf16x8*)&Ks[1][n * 16 + fr][swz8];
        }

#pragma unroll
        for (int qs = 0; qs < 2; qs++) {
            // S^T tiles (log2-domain scores; Q pre-scaled)
            f32x4 st[4] = {};
#pragma unroll
            for (int n = 0; n < 4; n++) {
                st[n] = __builtin_amdgcn_mfma_f32_16x16x32_bf16(kf[n][0], qf[qs][0], st[n], 0, 0, 0);
                st[n] = __builtin_amdgcn_mfma_f32_16x16x32_bf16(kf[n][1], qf[qs][1], st[n], 0, 0, 0);
            }
            if (kt == 11) {   // mask invalid keys (uniform branch, last tile only)
#pragma unroll
                for (int n = 0; n < 4; n++) {
                    int kb = 704 + n * 16 + fq * 4;
#pragma unroll
                    for (int r = 0; r < 4; r++)
                        if (kb + r >= SS) st[n][r] = -1e30f;
                }
            }
            // online softmax: all 16 values in this lane share one qrow
            float mx = -1e30f;
#pragma unroll
            for (int n = 0; n < 4; n++)
#pragma unroll
                for (int r = 0; r < 4; r++) mx = fmaxf(mx, st[n][r]);
            mx = fmaxf(mx, __shfl_xor(mx, 16));
            mx = fmaxf(mx, __shfl_xor(mx, 32));
            float mnew = fmaxf(m_[qs], mx);
            float alpha = exp2f(m_[qs] - mnew);
            m_[qs] = mnew;
            float ls = 0.f;
#pragma unroll
            for (int n = 0; n < 4; n++)
#pragma unroll
                for (int r = 0; r < 4; r++) {
                    float p = exp2f(st[n][r] - mnew);
                    st[n][r] = p;
                    ls += p;
                }
            ls += __shfl_xor(ls, 16);
            ls += __shfl_xor(ls, 32);
            l_[qs] = l_[qs] * alpha + ls;
#pragma unroll
            for (int dt = 0; dt < 4; dt++)
#pragma unroll
                for (int r = 0; r < 4; r++) o_acc[qs][dt][r] *= alpha;
            // store P: plane=key/32, row=qrow, col=key%32 (8B aligned writes)
#pragma unroll
            for (int n = 0; n < 4; n++) {
                __align__(8) bf16 tb[4];
#pragma unroll
                for (int r = 0; r < 4; r++) tb[r] = __float2bfloat16(st[n][r]);
                *(unsigned long long*)&Ps[w][n >> 1][qs * 16 + fr][(n & 1) * 16 + fq * 4] =
                    *(unsigned long long*)tb;
            }
        }
        // PV: O^T += V^T · P  (A = V-frag swizzled, B = P natural/padded)
        bf16x8 pf[2][2];
#pragma unroll
        for (int qs = 0; qs < 2; qs++) {
            pf[qs][0] = *(const bf16x8*)&Ps[w][0][qs * 16 + fr][fq * 8];
            pf[qs][1] = *(const bf16x8*)&Ps[w][1][qs * 16 + fr][fq * 8];
        }
#pragma unroll
        for (int dt = 0; dt < 4; dt++) {
            bf16x8 vf0 = *(const bf16x8*)&Vs[0][dt * 16 + fr][swz8];
            bf16x8 vf1 = *(const bf16x8*)&Vs[1][dt * 16 + fr][swz8];
#pragma unroll
            for (int qs = 0; qs < 2; qs++) {
                o_acc[qs][dt] = __builtin_amdgcn_mfma_f32_16x16x32_bf16(vf0, pf[qs][0], o_acc[qs][dt], 0, 0, 0);
                o_acc[qs][dt] = __builtin_amdgcn_mfma_f32_16x16x32_bf16(vf1, pf[qs][1], o_acc[qs][dt], 0, 0, 0);
            }
        }
    }

    // epilogue: O^T C-layout row=d=dt*16+fq*4+r, col=qrow -> ao[s][h*64+d]
#pragma unroll
    for (int qs = 0; qs < 2; qs++) {
        int srow = q0 + w * 32 + qs * 16 + fr;
        if (srow < SS) {
            float inv = 1.f / l_[qs];
            bf16* dst = ao + ((size_t)(b * SS + srow) * 8 + h) * 64;
#pragma unroll
            for (int dt = 0; dt < 4; dt++) {
                __align__(8) bf16 tb[4];
#pragma unroll
                for (int r = 0; r < 4; r++)
                    tb[r] = __float2bfloat16(o_acc[qs][dt][r] * inv);
                *(unsigned long long*)(dst + dt * 16 + fq * 4) =
                    *(unsigned long long*)tb;
            }
        }
    }
}

// ---------------------------------------------------------------------------
// bf16 MFMA GEMM (m97 pattern + XOR swizzle): C = act(A[M,K] @ W[N,K]^T + b)
// ---------------------------------------------------------------------------
template <bool RELU, bool OUT_BF16>
__global__ __launch_bounds__(256) void k_gemm_mfma(const bf16* __restrict__ A,
                                                   const bf16* __restrict__ W,
                                                   const float* __restrict__ bias,
                                                   void* __restrict__ Cout,
                                                   int M, int N, int K) {
    __shared__ __align__(16) bf16 As[128 * 32];
    __shared__ __align__(16) bf16 Ws[128 * 32];
    int t = threadIdx.x;
    int wave = t >> 6, lane = t & 63;
    int m0 = blockIdx.x * 128, n0 = blockIdx.y * 128;
    int wm = (wave >> 1) * 64, wn = (wave & 1) * 64;
    int fr = lane & 15, fq = lane >> 4;
    int csw = ((lane & 3) ^ ((lane >> 3) & 3)) * 8;   // swizzled global chunk
    int swz8 = (fq ^ ((fr >> 1) & 3)) * 8;            // swizzled frag-read col

    f32x4 acc[4][4] = {};

    int r0 = wave * 16 + (lane >> 2);
    int r1 = r0 + 64;

    for (int k0 = 0; k0 < K; k0 += 32) {
        __syncthreads();
        __builtin_amdgcn_global_load_lds(GPTR(A + (size_t)(m0 + r0) * K + k0 + csw),
                                         LPTR((char*)As + (wave << 10)), 16, 0, 0);
        __builtin_amdgcn_global_load_lds(GPTR(A + (size_t)(m0 + r1) * K + k0 + csw),
                                         LPTR((char*)As + (wave << 10) + 4096), 16, 0, 0);
        __builtin_amdgcn_global_load_lds(GPTR(W + (size_t)(n0 + r0) * K + k0 + csw),
                                         LPTR((char*)Ws + (wave << 10)), 16, 0, 0);
        __builtin_amdgcn_global_load_lds(GPTR(W + (size_t)(n0 + r1) * K + k0 + csw),
                                         LPTR((char*)Ws + (wave << 10) + 4096), 16, 0, 0);
        __syncthreads();

        bf16x8 af[4], bfr[4];
#pragma unroll
        for (int i = 0; i < 4; i++)
            af[i] = *(const bf16x8*)(As + (wm + i * 16 + fr) * 32 + swz8);
#pragma unroll
        for (int i = 0; i < 4; i++)
            bfr[i] = *(const bf16x8*)(Ws + (wn + i * 16 + fr) * 32 + swz8);
#pragma unroll
        for (int mi = 0; mi < 4; mi++)
#pragma unroll
            for (int ni = 0; ni < 4; ni++)
                acc[mi][ni] = __builtin_amdgcn_mfma_f32_16x16x32_bf16(
                    af[mi], bfr[ni], acc[mi][ni], 0, 0, 0);
    }

    float bv[4];
#pragma unroll
    for (int ni = 0; ni < 4; ni++) bv[ni] = bias[n0 + wn + ni * 16 + fr];
#pragma unroll
    for (int mi = 0; mi < 4; mi++) {
#pragma unroll
        for (int r = 0; r < 4; r++) {
            int mg = m0 + wm + mi * 16 + fq * 4 + r;
#pragma unroll
            for (int ni = 0; ni < 4; ni++) {
                float val = acc[mi][ni][r] + bv[ni];
                if (RELU) val = fmaxf(val, 0.f);
                int ng = n0 + wn + ni * 16 + fr;
                if (OUT_BF16)
                    ((bf16*)Cout)[(size_t)mg * N + ng] = __float2bfloat16(val);
                else
                    ((float*)Cout)[(size_t)mg * N + ng] = val;
            }
        }
    }
}

// ---------------------------------------------------------------------------
// Fused residual add + LayerNorm.
// BRES16: residual `bres` is bf16 (else fp32). WF32: also write fp32 out.
// ---------------------------------------------------------------------------
template <bool BRES16, bool WF32>
__global__ __launch_bounds__(128) void k_add_ln(const float* __restrict__ a,
                                                const void* __restrict__ bres,
                                                const float* __restrict__ w,
                                                const float* __restrict__ bias,
                                                float* out,
                                                bf16* __restrict__ out16) {
    int row = blockIdx.x;
    int t = threadIdx.x;
    float4 xa = ((const float4*)(a + (size_t)row * DD))[t];
    float4 xb;
    if (BRES16) {
        ushort4 ub = ((const ushort4*)((const bf16*)bres + (size_t)row * DD))[t];
        xb.x = __bfloat162float(*(bf16*)&ub.x);
        xb.y = __bfloat162float(*(bf16*)&ub.y);
        xb.z = __bfloat162float(*(bf16*)&ub.z);
        xb.w = __bfloat162float(*(bf16*)&ub.w);
    } else {
        xb = ((const float4*)((const float*)bres + (size_t)row * DD))[t];
    }
    float4 vv;
    vv.x = xa.x + xb.x; vv.y = xa.y + xb.y;
    vv.z = xa.z + xb.z; vv.w = xa.w + xb.w;
    float s  = vv.x + vv.y + vv.z + vv.w;
    float sq = vv.x * vv.x + vv.y * vv.y + vv.z * vv.z + vv.w * vv.w;
#pragma unroll
    for (int off = 32; off > 0; off >>= 1) {
        s  += __shfl_down(s, off);
        sq += __shfl_down(sq, off);
    }
    __shared__ float red[4];
    if ((t & 63) == 0) { red[(t >> 6) * 2] = s; red[(t >> 6) * 2 + 1] = sq; }
    __syncthreads();
    float S1 = red[0] + red[2], S2 = red[1] + red[3];
    float mean = S1 * (1.f / DD);
    float var  = S2 * (1.f / DD) - mean * mean;
    float inv  = rsqrtf(var + 1e-5f);
    float4 wv = ((const float4*)w)[t];
    float4 bv = ((const float4*)bias)[t];
    float4 o;
    o.x = (vv.x - mean) * inv * wv.x + bv.x;
    o.y = (vv.y - mean) * inv * wv.y + bv.y;
    o.z = (vv.z - mean) * inv * wv.z + bv.z;
    o.w = (vv.w - mean) * inv * wv.w + bv.w;
    if (WF32)
        ((float4*)(out + (size_t)row * DD))[t] = o;
    bf16 h0 = __float2bfloat16(o.x), h1 = __float2bfloat16(o.y);
    bf16 h2 = __float2bfloat16(o.z), h3 = __float2bfloat16(o.w);
    ushort4 u;
    u.x = *(unsigned short*)&h0; u.y = *(unsigned short*)&h1;
    u.z = *(unsigned short*)&h2; u.w = *(unsigned short*)&h3;
    ((ushort4*)(out16 + (size_t)row * DD))[t] = u;
}

// ---------------------------------------------------------------------------
extern "C" void kernel_launch(void* const* d_in, const int* in_sizes, int n_in,
                              void* d_out, int out_size, void* d_ws, size_t ws_size,
                              hipStream_t stream) {
    const int*   x    = (const int*)d_in[0];
    const float* emb  = (const float*)d_in[1];
    const float* pe   = (const float*)d_in[2];
    const float* Wq   = (const float*)d_in[3];
    const float* Wk   = (const float*)d_in[4];
    const float* Wv   = (const float*)d_in[5];
    const float* Wo   = (const float*)d_in[6];
    const float* bo   = (const float*)d_in[7];
    const float* ln1w = (const float*)d_in[8];
    const float* ln1b = (const float*)d_in[9];
    const float* W1   = (const float*)d_in[10];
    const float* b1   = (const float*)d_in[11];
    const float* W2   = (const float*)d_in[12];
    const float* b2   = (const float*)d_in[13];
    const float* ln2w = (const float*)d_in[14];
    const float* ln2b = (const float*)d_in[15];

    float* h  = (float*)d_out;
    float* ws = (float*)d_ws;
    // Region A [0, NBUF): qk bf16 [MROWS][128] -> wo_out fp32 -> ff fp32
    bf16*  qkbuf  = (bf16*)ws;
    float* wo_out = ws;
    float* ff     = ws;
    // Region B+C [NBUF, 3*NBUF): v/vt/wqkv (dead after attn) -> f1b bf16 [23808][2048]
    bf16*  v_buf  = (bf16*)(ws + NBUF);
    bf16*  vt_buf = (bf16*)(ws + NBUF + NBUF / 2);
    bf16*  wqkv   = vt_buf;            // overlaid; dead before vT written
    bf16*  f1b    = (bf16*)(ws + NBUF);
    // Region D [3*NBUF, 3.5*NBUF): aob -> n1b (bf16 [NROWS][512])
    bf16*  regD   = (bf16*)(ws + 3 * NBUF);
    // Region E [3.5*NBUF, 4*NBUF): h16
    bf16*  h16    = regD + NBUF;
    // Weights (bf16)
    bf16*  wob16  = h16 + NBUF;
    bf16*  w1b16  = wob16 + (size_t)LL * DD * DD;
    bf16*  w2b16  = w1b16 + (size_t)LL * EXPAND * DD * DD;

    k_f2b<<<2048, 256, 0, stream>>>(Wo, wob16, LL * DD * DD);
    k_f2b<<<4096, 256, 0, stream>>>(W1, w1b16, LL * EXPAND * DD * DD);
    k_f2b<<<4096, 256, 0, stream>>>(W2, w2b16, LL * EXPAND * DD * DD);
    k_embed<<<NROWS, 128, 0, stream>>>(x, emb, pe, h, h16);

    for (int l = 0; l < LL; l++) {
        k_f2b<<<16, 256, 0, stream>>>(Wq + (size_t)l * 4096, wqkv, 4096);
        k_f2b<<<16, 256, 0, stream>>>(Wk + (size_t)l * 4096, wqkv + 4096, 4096);
        k_f2b<<<16, 256, 0, stream>>>(Wv + (size_t)l * 4096, wqkv + 8192, 4096);
        k_qkv_mfma<<<MROWS / 128, 256, 0, stream>>>(h16, wqkv, qkbuf, v_buf);
        k_vt<<<dim3(256, 12), 256, 0, stream>>>(v_buf, vt_buf);
        k_attn_mfma<<<dim3(256, 6), 256, 0, stream>>>(qkbuf, vt_buf, regD);
        k_gemm_mfma<false, false><<<dim3(NROWS / 128, DD / 128), 256, 0, stream>>>(
            regD, wob16 + (size_t)l * DD * DD, bo + (size_t)l * DD, wo_out,
            NROWS, DD, DD);
        // n1 kept only as bf16 (regD); frees region C for full-size f1b
        k_add_ln<false, false><<<NROWS, 128, 0, stream>>>(wo_out, h,
            ln1w + (size_t)l * DD, ln1b + (size_t)l * DD, nullptr, regD);
        k_gemm_mfma<true, true><<<dim3(NROWS / 128, (EXPAND * DD) / 128), 256, 0, stream>>>(
            regD, w1b16 + (size_t)l * EXPAND * DD * DD, b1 + (size_t)l * EXPAND * DD,
            f1b, NROWS, EXPAND * DD, DD);
        k_gemm_mfma<false, false><<<dim3(NROWS / 128, DD / 128), 256, 0, stream>>>(
            f1b, w2b16 + (size_t)l * DD * EXPAND * DD, b2 + (size_t)l * DD,
            ff, NROWS, DD, EXPAND * DD);
        k_add_ln<true, true><<<NROWS, 128, 0, stream>>>(ff, regD,
            ln2w + (size_t)l * DD, ln2b + (size_t)l * DD, h, h16);
    }
}